// Round 2
// baseline (2459.288 us; speedup 1.0000x reference)
//
// MultiheadSelectiveAttentionWithTokenPruning — MI355X round 1
//
// Round-1 change: evict_kernel rewritten as SINGLE-WAVE (64 lanes, 32
// cols/lane in registers, no __syncthreads). The old 256-thread version's
// two barriers per iteration drained vmcnt(0), serializing the S-row
// prefetch latency into the 1024-step sequential chain (~1920 cyc/iter).
// New version: register accumulators + sentinel (-1e30) for evicted
// columns, tournament-tree local argmax (tie -> min m), u64 butterfly
// shuffle reduce, double-buffered row prefetch that stays in flight.
//
// Pipeline (all on `stream`, graph-capture safe, no statics):
//  1  cast_x      : X fp32 -> Xhi/Xlo bf16 (split for bf16x3 GEMM)
//  2  cast_w x4   : W fp32 -> W^T bf16 (hi[+lo for Wq/Wk])
//  3  gemm split  : Yq = X@Wq  (hi*hi + hi*lo + lo*hi)  ~fp32 accuracy
//  4  gemm split  : Yk = X@Wk
//  5  gemm        : Yv = X@Wv  (plain bf16)
//  6-8 lnpack     : LN + pack to (B,H,N,Dh) bf16, head-0 fp32 copies
//  9  s_kernel    : S[b,n,m] = relu(q0.k0/8), causal/diag/col0-zeroed
// 10  p_kernel    : column partial sums of S rows 0..1023
// 11  evict       : 1024 sequential argmax evictions (single wave/batch)
// 12  flash       : all 16 heads, online softmax, mask = causal && n<evt[m]
// 13  gemm        : out = Ob @ Wo -> d_out fp32

#include <hip/hip_runtime.h>

#define B_    2
#define N_    2048
#define D_    1024
#define H_    16
#define DH_   64
#define M_    2048
#define ROWS_ 4096
#define BUD_  1024

typedef unsigned short u16;
typedef unsigned int   u32;
typedef unsigned long long u64;
typedef __attribute__((ext_vector_type(8))) short short8;
typedef __attribute__((ext_vector_type(4))) float floatx4;

__device__ __forceinline__ u16 f2b(float f) {
    u32 u = __float_as_uint(f);
    return (u16)((u + 0x7FFFu + ((u >> 16) & 1u)) >> 16);   // RNE
}
__device__ __forceinline__ float b2f(u16 h) {
    return __uint_as_float(((u32)h) << 16);
}

// ---------------------------------------------------------------- cast X
__global__ __launch_bounds__(256) void cast_x_kernel(
    const float* __restrict__ X, u16* __restrict__ Xhi, u16* __restrict__ Xlo)
{
    int idx = (blockIdx.x * 256 + threadIdx.x) * 4;
    float4 v = *(const float4*)&X[idx];
    u16 h0 = f2b(v.x), h1 = f2b(v.y), h2 = f2b(v.z), h3 = f2b(v.w);
    ushort4 hv; hv.x = h0; hv.y = h1; hv.z = h2; hv.w = h3;
    *(ushort4*)&Xhi[idx] = hv;
    ushort4 lv;
    lv.x = f2b(v.x - b2f(h0)); lv.y = f2b(v.y - b2f(h1));
    lv.z = f2b(v.z - b2f(h2)); lv.w = f2b(v.w - b2f(h3));
    *(ushort4*)&Xlo[idx] = lv;
}

// ------------------------------------------------- cast + transpose W
__global__ __launch_bounds__(1024) void cast_w_kernel(
    const float* __restrict__ W, u16* __restrict__ Whi, u16* __restrict__ Wlo,
    int do_lo)
{
    __shared__ float tile[32][33];
    int tx = threadIdx.x, ty = threadIdx.y;
    int x = blockIdx.x * 32 + tx, y = blockIdx.y * 32 + ty;
    tile[ty][tx] = W[(size_t)y * D_ + x];
    __syncthreads();
    float v = tile[tx][ty];
    int n = blockIdx.x * 32 + ty, k = blockIdx.y * 32 + tx;
    u16 h = f2b(v);
    Whi[(size_t)n * D_ + k] = h;
    if (do_lo) Wlo[(size_t)n * D_ + k] = f2b(v - b2f(h));
}

// ------------------------------------------------------------- GEMM
// C[4096][1024] = A[4096][1024] @ Bt^T   (Bt stored [n][k])
// mode 1: C = Ah*Bh + Ah*Bl + Al*Bh  (bf16x3 split, ~fp32 precision)
__global__ __launch_bounds__(256) void gemm_kernel(
    const u16* __restrict__ Ah, const u16* __restrict__ Al,
    const u16* __restrict__ Bh, const u16* __restrict__ Bl,
    int mode, float* __restrict__ C)
{
    __shared__ __align__(16) u16 sAh[128 * 32];
    __shared__ __align__(16) u16 sBh[128 * 32];
    __shared__ __align__(16) u16 sAl[128 * 32];
    __shared__ __align__(16) u16 sBl[128 * 32];
    int tid = threadIdx.x;
    int lane = tid & 63, wv = tid >> 6;
    int wr = wv >> 1, wc = wv & 1;
    int quad = lane >> 4, l16 = lane & 15;
    int m0 = blockIdx.y * 128, n0 = blockIdx.x * 128;

    floatx4 acc[4][4];
    floatx4 zero = {0.f, 0.f, 0.f, 0.f};
#pragma unroll
    for (int i = 0; i < 4; ++i)
#pragma unroll
        for (int j = 0; j < 4; ++j) acc[i][j] = zero;

    for (int k0 = 0; k0 < 1024; k0 += 32) {
#pragma unroll
        for (int it = 0; it < 2; ++it) {
            int e = (tid + it * 256) * 8;
            int r = e >> 5, c = e & 31;
            *(uint4*)&sAh[e] = *(const uint4*)&Ah[(size_t)(m0 + r) * 1024 + k0 + c];
            *(uint4*)&sBh[e] = *(const uint4*)&Bh[(size_t)(n0 + r) * 1024 + k0 + c];
            if (mode) {
                *(uint4*)&sAl[e] = *(const uint4*)&Al[(size_t)(m0 + r) * 1024 + k0 + c];
                *(uint4*)&sBl[e] = *(const uint4*)&Bl[(size_t)(n0 + r) * 1024 + k0 + c];
            }
        }
        __syncthreads();
        short8 ah[4], al[4], bh[4], bl[4];
#pragma unroll
        for (int x = 0; x < 4; ++x) {
            int ra = (wr * 64 + x * 16 + l16) * 32 + quad * 8;
            int rb = (wc * 64 + x * 16 + l16) * 32 + quad * 8;
            ah[x] = *(const short8*)&sAh[ra];
            bh[x] = *(const short8*)&sBh[rb];
            if (mode) {
                al[x] = *(const short8*)&sAl[ra];
                bl[x] = *(const short8*)&sBl[rb];
            }
        }
#pragma unroll
        for (int mi = 0; mi < 4; ++mi)
#pragma unroll
            for (int ni = 0; ni < 4; ++ni) {
                acc[mi][ni] = __builtin_amdgcn_mfma_f32_16x16x32_bf16(
                    ah[mi], bh[ni], acc[mi][ni], 0, 0, 0);
                if (mode) {
                    acc[mi][ni] = __builtin_amdgcn_mfma_f32_16x16x32_bf16(
                        ah[mi], bl[ni], acc[mi][ni], 0, 0, 0);
                    acc[mi][ni] = __builtin_amdgcn_mfma_f32_16x16x32_bf16(
                        al[mi], bh[ni], acc[mi][ni], 0, 0, 0);
                }
            }
        __syncthreads();
    }
    // C/D layout: col = lane&15, row = (lane>>4)*4 + reg   [verified m89/m91]
#pragma unroll
    for (int mi = 0; mi < 4; ++mi)
#pragma unroll
        for (int ni = 0; ni < 4; ++ni)
#pragma unroll
            for (int r = 0; r < 4; ++r) {
                int row = m0 + wr * 64 + mi * 16 + quad * 4 + r;
                int col = n0 + wc * 64 + ni * 16 + l16;
                C[(size_t)row * 1024 + col] = acc[mi][ni][r];
            }
}

// ----------------------------------------------------- LayerNorm + pack
__global__ __launch_bounds__(256) void lnpack_kernel(
    const float* __restrict__ Y, const float* __restrict__ gamma,
    const float* __restrict__ beta, u16* __restrict__ Pk,
    float* __restrict__ head0, int do_ln)
{
    int r = blockIdx.x;
    int tid = threadIdx.x;
    float4 v = *(const float4*)&Y[(size_t)r * D_ + tid * 4];
    float mu = 0.f, rsig = 1.f;
    __shared__ float sS[4], sQ[4];
    if (do_ln) {
        float s = v.x + v.y + v.z + v.w;
        float q = v.x * v.x + v.y * v.y + v.z * v.z + v.w * v.w;
#pragma unroll
        for (int d = 1; d < 64; d <<= 1) { s += __shfl_xor(s, d); q += __shfl_xor(q, d); }
        if ((tid & 63) == 0) { sS[tid >> 6] = s; sQ[tid >> 6] = q; }
        __syncthreads();
        s = sS[0] + sS[1] + sS[2] + sS[3];
        q = sQ[0] + sQ[1] + sQ[2] + sQ[3];
        mu = s * (1.f / 1024.f);
        float var = q * (1.f / 1024.f) - mu * mu;
        rsig = rsqrtf(var + 1e-5f);
    }
    int b = r >> 11, n = r & 2047;
    float xs[4] = {v.x, v.y, v.z, v.w};
#pragma unroll
    for (int j = 0; j < 4; ++j) {
        int c = tid * 4 + j;
        float val = do_ln ? ((xs[j] - mu) * rsig * gamma[c] + beta[c]) : xs[j];
        int h = c >> 6, dh = c & 63;
        Pk[(((size_t)b * H_ + h) * N_ + n) * DH_ + dh] = f2b(val);
        if (head0 && c < 64) head0[(size_t)r * 64 + c] = val;
    }
}

// -------------------------------------------- head-0 selection scores S
__global__ void s_kernel(const float* __restrict__ q0,
                         const float* __restrict__ k0, float* __restrict__ S)
{
    int b = blockIdx.z;
    int n0 = blockIdx.y * 16, m0 = blockIdx.x * 16;
    int tx = threadIdx.x, ty = threadIdx.y;
    int n = n0 + ty, m = m0 + tx;
    float* out = S + ((size_t)b * N_ + n) * M_ + m;
    if (m0 > n0 + 15) { *out = 0.f; return; }   // fully above diagonal
    __shared__ float sq[16][65], sk[16][65];
    int tid = ty * 16 + tx;
    {
        int rr = tid >> 4, cc = (tid & 15) * 4;
        float4 qa = *(const float4*)&q0[((size_t)b * N_ + n0 + rr) * 64 + cc];
        sq[rr][cc] = qa.x; sq[rr][cc + 1] = qa.y; sq[rr][cc + 2] = qa.z; sq[rr][cc + 3] = qa.w;
        float4 ka = *(const float4*)&k0[((size_t)b * N_ + m0 + rr) * 64 + cc];
        sk[rr][cc] = ka.x; sk[rr][cc + 1] = ka.y; sk[rr][cc + 2] = ka.z; sk[rr][cc + 3] = ka.w;
    }
    __syncthreads();
    float acc = 0.f;
#pragma unroll 8
    for (int d = 0; d < 64; ++d) acc += sq[ty][d] * sk[tx][d];
    float val;
    if (m < n && m != 0) val = fmaxf(acc * 0.125f, 0.f); else val = 0.f;
    *out = val;
}

// -------------------------------- partial column sums of S rows 0..1023
__global__ __launch_bounds__(256) void p_kernel(const float* __restrict__ S,
                                                float* __restrict__ P)
{
    int b = blockIdx.z, c = blockIdx.y;
    int m = blockIdx.x * 256 + threadIdx.x;
    const float* base = S + ((size_t)b * N_ + c * 128) * M_ + m;
    float s = 0.f;
    for (int j = 0; j < 128; ++j) s += base[(size_t)j * M_];
    P[((size_t)b * 8 + c) * M_ + m] = s;
}

// --------------------------------------------- sequential greedy eviction
// Single wave per batch. Lane t owns columns m = j*256 + t*4 + c (j<8,c<4),
// element index e = j*4+c (ascending e == ascending m within a lane).
// Evicted columns -> cum = -1e30 (absorbing: rr >= 0, so -1e30 + rr stays
// -1e30; the monotone u32 key maps it below every non-negative value).
// Columns m >= i sit at exactly 0 (causal zeros) and can never win: any
// real candidate with score 0 has smaller m and wins the tie (col 0 is a
// permanent 0-valued candidate at m=0 until evicted; if all real
// candidates are positive the max is positive and 0 loses).
__device__ __forceinline__ void evict_step(
    float (&cum)[32], float (&rr)[32], int i, int t, int b,
    const float* __restrict__ Sb, int* __restrict__ evt)
{
    // local argmax: tournament tree, pairs ascending-m, >= keeps left
    // => first-max == smallest m within lane (matches jnp.argmax)
    float v[16]; u32 ei[16];
#pragma unroll
    for (int k = 0; k < 16; ++k) {
        bool left = cum[2 * k] >= cum[2 * k + 1];
        v[k]  = left ? cum[2 * k] : cum[2 * k + 1];
        ei[k] = left ? (u32)(2 * k) : (u32)(2 * k + 1);
    }
#pragma unroll
    for (int w = 8; w >= 1; w >>= 1)
#pragma unroll
        for (int k = 0; k < w; ++k) {
            bool left = v[2 * k] >= v[2 * k + 1];
            v[k]  = left ? v[2 * k] : v[2 * k + 1];
            ei[k] = left ? ei[2 * k] : ei[2 * k + 1];
        }
    int bestm = ((int)(ei[0] >> 2) << 8) | (t << 2) | (int)(ei[0] & 3);
    // monotone float->u32 key (handles the -1e30 sentinel's sign bit)
    u32 bits = __float_as_uint(v[0]);
    u32 key = bits ^ (((u32)((int)bits >> 31)) | 0x80000000u);
    u64 pk = ((u64)key << 32) | (u32)(2048 - bestm);   // tie -> min m
#pragma unroll
    for (int d = 1; d < 64; d <<= 1) {
        u64 o = __shfl_xor(pk, d);
        if (o > pk) pk = o;
    }
    int mstar = 2048 - (int)(pk & 0xFFFFFFFFu);
    bool mine = ((mstar >> 2) & 63) == t;
    if (mine) evt[b * M_ + mstar] = i;
    int estar = ((mstar >> 8) << 2) | (mstar & 3);
#pragma unroll
    for (int k = 0; k < 32; ++k) {
        float nv = cum[k] + rr[k];
        cum[k] = (mine && estar == k) ? -1e30f : nv;
    }
    // refill rr with row i+2 (clamped; clamp rows are never consumed)
    int nr = i + 2 < 2048 ? i + 2 : 2047;
#pragma unroll
    for (int j = 0; j < 8; ++j)
        *(float4*)&rr[j * 4] =
            *(const float4*)&Sb[(size_t)nr * M_ + j * 256 + t * 4];
}

__global__ __launch_bounds__(64) void evict_kernel(
    const float* __restrict__ S, const float* __restrict__ P,
    int* __restrict__ evt)
{
    int b = blockIdx.x, t = threadIdx.x;
    const float* Sb = S + (size_t)b * N_ * M_;
    float cum[32];
#pragma unroll
    for (int j = 0; j < 8; ++j) {
        float4 s4 = {0.f, 0.f, 0.f, 0.f};
#pragma unroll
        for (int ch = 0; ch < 8; ++ch) {
            float4 p4 = *(const float4*)&P[((size_t)b * 8 + ch) * M_ + j * 256 + t * 4];
            s4.x += p4.x; s4.y += p4.y; s4.z += p4.z; s4.w += p4.w;
        }
        cum[j * 4 + 0] = s4.x; cum[j * 4 + 1] = s4.y;
        cum[j * 4 + 2] = s4.z; cum[j * 4 + 3] = s4.w;
        int4 init = {0x3FFFFFFF, 0x3FFFFFFF, 0x3FFFFFFF, 0x3FFFFFFF};
        *(int4*)&evt[b * M_ + j * 256 + t * 4] = init;
    }
    float rrA[32], rrB[32];
#pragma unroll
    for (int j = 0; j < 8; ++j) {
        *(float4*)&rrA[j * 4] = *(const float4*)&Sb[(size_t)1024 * M_ + j * 256 + t * 4];
        *(float4*)&rrB[j * 4] = *(const float4*)&Sb[(size_t)1025 * M_ + j * 256 + t * 4];
    }
    for (int i = 1024; i < 2048; i += 2) {
        evict_step(cum, rrA, i,     t, b, Sb, evt);
        evict_step(cum, rrB, i + 1, t, b, Sb, evt);
    }
}

// ------------------------------------------------------ flash attention
__global__ __launch_bounds__(256) void flash_kernel(
    const u16* __restrict__ Qb, const u16* __restrict__ Kb,
    const u16* __restrict__ Vb, const int* __restrict__ evt,
    u16* __restrict__ Ob)
{
    int bh = blockIdx.y;
    int b = bh >> 4, h = bh & 15;
    int q0 = blockIdx.x * 64;
    int tid = threadIdx.x, lane = tid & 63, w = tid >> 6;
    int quad = lane >> 4, l16 = lane & 15;
    const u16* Qh = Qb + (size_t)bh * N_ * DH_;
    const u16* Kh = Kb + (size_t)bh * N_ * DH_;
    const u16* Vh = Vb + (size_t)bh * N_ * DH_;
    __shared__ __align__(16) u16 sK[64 * 64];
    __shared__ __align__(16) u16 sV[64 * 64];     // transposed [dh][key]
    __shared__ __align__(16) u16 sP[4][16 * 64];  // wave-private P
    __shared__ int sevt[64];

    short8 aq0 = *(const short8*)&Qh[(size_t)(q0 + w * 16 + l16) * 64 + quad * 8];
    short8 aq1 = *(const short8*)&Qh[(size_t)(q0 + w * 16 + l16) * 64 + quad * 8 + 32];

    floatx4 zero = {0.f, 0.f, 0.f, 0.f};
    floatx4 accO[4];
#pragma unroll
    for (int d = 0; d < 4; ++d) accO[d] = zero;
    float m_i[4] = {-1e30f, -1e30f, -1e30f, -1e30f};
    float l_i[4] = {0.f, 0.f, 0.f, 0.f};

    int ktiles = blockIdx.x + 1;
    for (int kt = 0; kt < ktiles; ++kt) {
        int k0 = kt * 64;
#pragma unroll
        for (int it = 0; it < 2; ++it) {
            int e = (tid + it * 256) * 8;
            int r = e >> 6, c = e & 63;
            *(uint4*)&sK[e] = *(const uint4*)&Kh[(size_t)(k0 + r) * 64 + c];
            uint4 vv = *(const uint4*)&Vh[(size_t)(k0 + r) * 64 + c];
            sV[(c + 0) * 64 + r] = (u16)(vv.x & 0xFFFF);
            sV[(c + 1) * 64 + r] = (u16)(vv.x >> 16);
            sV[(c + 2) * 64 + r] = (u16)(vv.y & 0xFFFF);
            sV[(c + 3) * 64 + r] = (u16)(vv.y >> 16);
            sV[(c + 4) * 64 + r] = (u16)(vv.z & 0xFFFF);
            sV[(c + 5) * 64 + r] = (u16)(vv.z >> 16);
            sV[(c + 6) * 64 + r] = (u16)(vv.w & 0xFFFF);
            sV[(c + 7) * 64 + r] = (u16)(vv.w >> 16);
        }
        if (tid < 64) sevt[tid] = evt[b * M_ + k0 + tid];
        __syncthreads();

        floatx4 lg[4];
        int nbase = q0 + w * 16 + quad * 4;
#pragma unroll
        for (int s = 0; s < 4; ++s) {
            floatx4 sc = zero;
            short8 bk0 = *(const short8*)&sK[(s * 16 + l16) * 64 + quad * 8];
            short8 bk1 = *(const short8*)&sK[(s * 16 + l16) * 64 + quad * 8 + 32];
            sc = __builtin_amdgcn_mfma_f32_16x16x32_bf16(aq0, bk0, sc, 0, 0, 0);
            sc = __builtin_amdgcn_mfma_f32_16x16x32_bf16(aq1, bk1, sc, 0, 0, 0);
            int m = k0 + s * 16 + l16;
            int ev = sevt[s * 16 + l16];
#pragma unroll
            for (int r = 0; r < 4; ++r) {
                int n = nbase + r;
                bool keep = (m <= n) && (n < ev);
                lg[s][r] = keep ? sc[r] * 0.125f : -1e30f;
            }
        }
        float mnew[4], scale[4], rs[4];
#pragma unroll
        for (int r = 0; r < 4; ++r) {
            float mx = fmaxf(fmaxf(lg[0][r], lg[1][r]), fmaxf(lg[2][r], lg[3][r]));
#pragma unroll
            for (int d = 1; d < 16; d <<= 1) mx = fmaxf(mx, __shfl_xor(mx, d));
            mnew[r] = fmaxf(m_i[r], mx);
            scale[r] = __expf(m_i[r] - mnew[r]);
            m_i[r] = mnew[r];
            rs[r] = 0.f;
        }
#pragma unroll
        for (int s = 0; s < 4; ++s)
#pragma unroll
            for (int r = 0; r < 4; ++r) {
                float p = __expf(lg[s][r] - mnew[r]);
                rs[r] += p;
                sP[w][(quad * 4 + r) * 64 + s * 16 + l16] = f2b(p);
            }
#pragma unroll
        for (int r = 0; r < 4; ++r) {
            float t_ = rs[r];
#pragma unroll
            for (int d = 1; d < 16; d <<= 1) t_ += __shfl_xor(t_, d);
            l_i[r] = l_i[r] * scale[r] + t_;
        }
#pragma unroll
        for (int dd = 0; dd < 4; ++dd) {
            accO[dd][0] *= scale[0]; accO[dd][1] *= scale[1];
            accO[dd][2] *= scale[2]; accO[dd][3] *= scale[3];
        }
        short8 ap0 = *(const short8*)&sP[w][l16 * 64 + quad * 8];
        short8 ap1 = *(const short8*)&sP[w][l16 * 64 + quad * 8 + 32];
#pragma unroll
        for (int dd = 0; dd < 4; ++dd) {
            short8 bv0 = *(const short8*)&sV[(dd * 16 + l16) * 64 + quad * 8];
            short8 bv1 = *(const short8*)&sV[(dd * 16 + l16) * 64 + quad * 8 + 32];
            accO[dd] = __builtin_amdgcn_mfma_f32_16x16x32_bf16(ap0, bv0, accO[dd], 0, 0, 0);
            accO[dd] = __builtin_amdgcn_mfma_f32_16x16x32_bf16(ap1, bv1, accO[dd], 0, 0, 0);
        }
        __syncthreads();
    }
#pragma unroll
    for (int dd = 0; dd < 4; ++dd)
#pragma unroll
        for (int r = 0; r < 4; ++r) {
            int n = q0 + w * 16 + quad * 4 + r;
            int col = h * 64 + dd * 16 + l16;
            Ob[((size_t)b * N_ + n) * D_ + col] = f2b(accO[dd][r] / l_i[r]);
        }
}

// ---------------------------------------------------------------- launch
extern "C" void kernel_launch(void* const* d_in, const int* in_sizes, int n_in,
                              void* d_out, int out_size, void* d_ws, size_t ws_size,
                              hipStream_t stream)
{
    (void)in_sizes; (void)n_in; (void)out_size; (void)ws_size;
    const float* X  = (const float*)d_in[0];
    const float* Wq = (const float*)d_in[1];
    const float* Wk = (const float*)d_in[2];
    const float* Wv = (const float*)d_in[3];
    const float* Wo = (const float*)d_in[4];
    const float* gq = (const float*)d_in[5];
    const float* bq = (const float*)d_in[6];
    const float* gk = (const float*)d_in[7];
    const float* bk = (const float*)d_in[8];

    char* p = (char*)d_ws;
    const size_t SZ_XH = (size_t)ROWS_ * D_ * 2;
    const size_t SZ_W  = (size_t)D_ * D_ * 2;
    const size_t SZ_Y  = (size_t)ROWS_ * D_ * 4;
    const size_t SZ_PK = (size_t)ROWS_ * D_ * 2;
    const size_t SZ_H0 = (size_t)ROWS_ * 64 * 4;

    size_t o = 0;
    u16* Xhi = (u16*)(p + o); o += SZ_XH;
    u16* Xlo = (u16*)(p + o); o += SZ_XH;
    u16* Wqh = (u16*)(p + o); o += SZ_W;
    u16* Wql = (u16*)(p + o); o += SZ_W;
    u16* Wkh = (u16*)(p + o); o += SZ_W;
    u16* Wkl = (u16*)(p + o); o += SZ_W;
    u16* Wvh = (u16*)(p + o); o += SZ_W;
    u16* Woh = (u16*)(p + o); o += SZ_W;
    float* Yq = (float*)(p + o); size_t oYq = o; o += SZ_Y;
    float* Yk = (float*)(p + o); o += SZ_Y;
    float* Yv = (float*)(p + o); o += SZ_Y;
    u16* Qb = (u16*)(p + o); o += SZ_PK;
    u16* Kb = (u16*)(p + o); o += SZ_PK;
    u16* Vb = (u16*)(p + o); o += SZ_PK;
    float* q0s = (float*)(p + o); o += SZ_H0;
    float* k0s = (float*)(p + o); o += SZ_H0;
    float* Pp  = (float*)(p + o); o += (size_t)B_ * 8 * M_ * 4;
    int* evt   = (int*)(p + o);  o += (size_t)B_ * M_ * 4;
    float* S = (float*)(p + oYq);   // overlay over Yq+Yk (dead after LN)
    u16* Ob  = Xhi;                 // overlay over Xhi (dead after X-GEMMs)

    cast_x_kernel<<<ROWS_ * D_ / (256 * 4), 256, 0, stream>>>(X, Xhi, Xlo);
    dim3 wgrid(32, 32), wblk(32, 32);
    cast_w_kernel<<<wgrid, wblk, 0, stream>>>(Wq, Wqh, Wql, 1);
    cast_w_kernel<<<wgrid, wblk, 0, stream>>>(Wk, Wkh, Wkl, 1);
    cast_w_kernel<<<wgrid, wblk, 0, stream>>>(Wv, Wvh, nullptr, 0);
    cast_w_kernel<<<wgrid, wblk, 0, stream>>>(Wo, Woh, nullptr, 0);

    dim3 ggrid(D_ / 128, ROWS_ / 128);
    gemm_kernel<<<ggrid, 256, 0, stream>>>(Xhi, Xlo, Wqh, Wql, 1, Yq);
    gemm_kernel<<<ggrid, 256, 0, stream>>>(Xhi, Xlo, Wkh, Wkl, 1, Yk);
    gemm_kernel<<<ggrid, 256, 0, stream>>>(Xhi, nullptr, Wvh, nullptr, 0, Yv);

    lnpack_kernel<<<ROWS_, 256, 0, stream>>>(Yq, gq, bq, Qb, q0s, 1);
    lnpack_kernel<<<ROWS_, 256, 0, stream>>>(Yk, gk, bk, Kb, k0s, 1);
    lnpack_kernel<<<ROWS_, 256, 0, stream>>>(Yv, nullptr, nullptr, Vb, nullptr, 0);

    s_kernel<<<dim3(M_ / 16, N_ / 16, B_), dim3(16, 16), 0, stream>>>(q0s, k0s, S);
    p_kernel<<<dim3(M_ / 256, 8, B_), 256, 0, stream>>>(S, Pp);
    evict_kernel<<<B_, 64, 0, stream>>>(S, Pp, evt);

    flash_kernel<<<dim3(N_ / 64, B_ * H_), 256, 0, stream>>>(Qb, Kb, Vb, evt, Ob);
    gemm_kernel<<<ggrid, 256, 0, stream>>>(Ob, nullptr, Woh, nullptr, 0, (float*)d_out);
}

// Round 3
// 2407.626 us; speedup vs baseline: 1.0215x; 1.0215x over previous
//
// MultiheadSelectiveAttentionWithTokenPruning — MI355X round 2
//
// Round-2 change: evict_kernel register discipline. Round-1's single-wave
// version needed 96+ persistent VGPRs (cum[32]+rrA[32]+rrB[32] as float
// arrays passed by reference) but the allocator gave 72 -> scratch spills
// (~16 float4 private-mem ops/iter, ~4400 cyc/iter, 1885 us). Now: state
// is floatx4 cum[8] + ONE prefetch buffer floatx4 rr[8] (pure SSA vector
// values, no address-taken arrays, no helper fn), __launch_bounds__(64,1)
// so the allocator targets 1 wave/EU and never spills. Prefetch distance
// 1 row: issued after the cum update, consumed at the end of the next
// step's argmax (~500 cyc of slack vs ~300 cyc L2/L3 latency). No
// barriers anywhere in the 1024-step sequential loop.
//
// Pipeline:
//  1  cast_x      : X fp32 -> Xhi/Xlo bf16 (split for bf16x3 GEMM)
//  2  cast_w x4   : W fp32 -> W^T bf16 (hi[+lo for Wq/Wk])
//  3  gemm split  : Yq = X@Wq  (hi*hi + hi*lo + lo*hi)  ~fp32 accuracy
//  4  gemm split  : Yk = X@Wk
//  5  gemm        : Yv = X@Wv  (plain bf16)
//  6-8 lnpack     : LN + pack to (B,H,N,Dh) bf16, head-0 fp32 copies
//  9  s_kernel    : S[b,n,m] = relu(q0.k0/8), causal/diag/col0-zeroed
// 10  p_kernel    : column partial sums of S rows 0..1023
// 11  evict       : 1024 sequential argmax evictions (single wave/batch)
// 12  flash       : all 16 heads, online softmax, mask = causal && n<evt[m]
// 13  gemm        : out = Ob @ Wo -> d_out fp32

#include <hip/hip_runtime.h>

#define B_    2
#define N_    2048
#define D_    1024
#define H_    16
#define DH_   64
#define M_    2048
#define ROWS_ 4096
#define BUD_  1024

typedef unsigned short u16;
typedef unsigned int   u32;
typedef unsigned long long u64;
typedef __attribute__((ext_vector_type(8))) short short8;
typedef __attribute__((ext_vector_type(4))) float floatx4;

__device__ __forceinline__ u16 f2b(float f) {
    u32 u = __float_as_uint(f);
    return (u16)((u + 0x7FFFu + ((u >> 16) & 1u)) >> 16);   // RNE
}
__device__ __forceinline__ float b2f(u16 h) {
    return __uint_as_float(((u32)h) << 16);
}

// ---------------------------------------------------------------- cast X
__global__ __launch_bounds__(256) void cast_x_kernel(
    const float* __restrict__ X, u16* __restrict__ Xhi, u16* __restrict__ Xlo)
{
    int idx = (blockIdx.x * 256 + threadIdx.x) * 4;
    float4 v = *(const float4*)&X[idx];
    u16 h0 = f2b(v.x), h1 = f2b(v.y), h2 = f2b(v.z), h3 = f2b(v.w);
    ushort4 hv; hv.x = h0; hv.y = h1; hv.z = h2; hv.w = h3;
    *(ushort4*)&Xhi[idx] = hv;
    ushort4 lv;
    lv.x = f2b(v.x - b2f(h0)); lv.y = f2b(v.y - b2f(h1));
    lv.z = f2b(v.z - b2f(h2)); lv.w = f2b(v.w - b2f(h3));
    *(ushort4*)&Xlo[idx] = lv;
}

// ------------------------------------------------- cast + transpose W
__global__ __launch_bounds__(1024) void cast_w_kernel(
    const float* __restrict__ W, u16* __restrict__ Whi, u16* __restrict__ Wlo,
    int do_lo)
{
    __shared__ float tile[32][33];
    int tx = threadIdx.x, ty = threadIdx.y;
    int x = blockIdx.x * 32 + tx, y = blockIdx.y * 32 + ty;
    tile[ty][tx] = W[(size_t)y * D_ + x];
    __syncthreads();
    float v = tile[tx][ty];
    int n = blockIdx.x * 32 + ty, k = blockIdx.y * 32 + tx;
    u16 h = f2b(v);
    Whi[(size_t)n * D_ + k] = h;
    if (do_lo) Wlo[(size_t)n * D_ + k] = f2b(v - b2f(h));
}

// ------------------------------------------------------------- GEMM
// C[4096][1024] = A[4096][1024] @ Bt^T   (Bt stored [n][k])
// mode 1: C = Ah*Bh + Ah*Bl + Al*Bh  (bf16x3 split, ~fp32 precision)
__global__ __launch_bounds__(256) void gemm_kernel(
    const u16* __restrict__ Ah, const u16* __restrict__ Al,
    const u16* __restrict__ Bh, const u16* __restrict__ Bl,
    int mode, float* __restrict__ C)
{
    __shared__ __align__(16) u16 sAh[128 * 32];
    __shared__ __align__(16) u16 sBh[128 * 32];
    __shared__ __align__(16) u16 sAl[128 * 32];
    __shared__ __align__(16) u16 sBl[128 * 32];
    int tid = threadIdx.x;
    int lane = tid & 63, wv = tid >> 6;
    int wr = wv >> 1, wc = wv & 1;
    int quad = lane >> 4, l16 = lane & 15;
    int m0 = blockIdx.y * 128, n0 = blockIdx.x * 128;

    floatx4 acc[4][4];
    floatx4 zero = {0.f, 0.f, 0.f, 0.f};
#pragma unroll
    for (int i = 0; i < 4; ++i)
#pragma unroll
        for (int j = 0; j < 4; ++j) acc[i][j] = zero;

    for (int k0 = 0; k0 < 1024; k0 += 32) {
#pragma unroll
        for (int it = 0; it < 2; ++it) {
            int e = (tid + it * 256) * 8;
            int r = e >> 5, c = e & 31;
            *(uint4*)&sAh[e] = *(const uint4*)&Ah[(size_t)(m0 + r) * 1024 + k0 + c];
            *(uint4*)&sBh[e] = *(const uint4*)&Bh[(size_t)(n0 + r) * 1024 + k0 + c];
            if (mode) {
                *(uint4*)&sAl[e] = *(const uint4*)&Al[(size_t)(m0 + r) * 1024 + k0 + c];
                *(uint4*)&sBl[e] = *(const uint4*)&Bl[(size_t)(n0 + r) * 1024 + k0 + c];
            }
        }
        __syncthreads();
        short8 ah[4], al[4], bh[4], bl[4];
#pragma unroll
        for (int x = 0; x < 4; ++x) {
            int ra = (wr * 64 + x * 16 + l16) * 32 + quad * 8;
            int rb = (wc * 64 + x * 16 + l16) * 32 + quad * 8;
            ah[x] = *(const short8*)&sAh[ra];
            bh[x] = *(const short8*)&sBh[rb];
            if (mode) {
                al[x] = *(const short8*)&sAl[ra];
                bl[x] = *(const short8*)&sBl[rb];
            }
        }
#pragma unroll
        for (int mi = 0; mi < 4; ++mi)
#pragma unroll
            for (int ni = 0; ni < 4; ++ni) {
                acc[mi][ni] = __builtin_amdgcn_mfma_f32_16x16x32_bf16(
                    ah[mi], bh[ni], acc[mi][ni], 0, 0, 0);
                if (mode) {
                    acc[mi][ni] = __builtin_amdgcn_mfma_f32_16x16x32_bf16(
                        ah[mi], bl[ni], acc[mi][ni], 0, 0, 0);
                    acc[mi][ni] = __builtin_amdgcn_mfma_f32_16x16x32_bf16(
                        al[mi], bh[ni], acc[mi][ni], 0, 0, 0);
                }
            }
        __syncthreads();
    }
    // C/D layout: col = lane&15, row = (lane>>4)*4 + reg   [verified m89/m91]
#pragma unroll
    for (int mi = 0; mi < 4; ++mi)
#pragma unroll
        for (int ni = 0; ni < 4; ++ni)
#pragma unroll
            for (int r = 0; r < 4; ++r) {
                int row = m0 + wr * 64 + mi * 16 + quad * 4 + r;
                int col = n0 + wc * 64 + ni * 16 + l16;
                C[(size_t)row * 1024 + col] = acc[mi][ni][r];
            }
}

// ----------------------------------------------------- LayerNorm + pack
__global__ __launch_bounds__(256) void lnpack_kernel(
    const float* __restrict__ Y, const float* __restrict__ gamma,
    const float* __restrict__ beta, u16* __restrict__ Pk,
    float* __restrict__ head0, int do_ln)
{
    int r = blockIdx.x;
    int tid = threadIdx.x;
    float4 v = *(const float4*)&Y[(size_t)r * D_ + tid * 4];
    float mu = 0.f, rsig = 1.f;
    __shared__ float sS[4], sQ[4];
    if (do_ln) {
        float s = v.x + v.y + v.z + v.w;
        float q = v.x * v.x + v.y * v.y + v.z * v.z + v.w * v.w;
#pragma unroll
        for (int d = 1; d < 64; d <<= 1) { s += __shfl_xor(s, d); q += __shfl_xor(q, d); }
        if ((tid & 63) == 0) { sS[tid >> 6] = s; sQ[tid >> 6] = q; }
        __syncthreads();
        s = sS[0] + sS[1] + sS[2] + sS[3];
        q = sQ[0] + sQ[1] + sQ[2] + sQ[3];
        mu = s * (1.f / 1024.f);
        float var = q * (1.f / 1024.f) - mu * mu;
        rsig = rsqrtf(var + 1e-5f);
    }
    int b = r >> 11, n = r & 2047;
    float xs[4] = {v.x, v.y, v.z, v.w};
#pragma unroll
    for (int j = 0; j < 4; ++j) {
        int c = tid * 4 + j;
        float val = do_ln ? ((xs[j] - mu) * rsig * gamma[c] + beta[c]) : xs[j];
        int h = c >> 6, dh = c & 63;
        Pk[(((size_t)b * H_ + h) * N_ + n) * DH_ + dh] = f2b(val);
        if (head0 && c < 64) head0[(size_t)r * 64 + c] = val;
    }
}

// -------------------------------------------- head-0 selection scores S
__global__ void s_kernel(const float* __restrict__ q0,
                         const float* __restrict__ k0, float* __restrict__ S)
{
    int b = blockIdx.z;
    int n0 = blockIdx.y * 16, m0 = blockIdx.x * 16;
    int tx = threadIdx.x, ty = threadIdx.y;
    int n = n0 + ty, m = m0 + tx;
    float* out = S + ((size_t)b * N_ + n) * M_ + m;
    if (m0 > n0 + 15) { *out = 0.f; return; }   // fully above diagonal
    __shared__ float sq[16][65], sk[16][65];
    int tid = ty * 16 + tx;
    {
        int rr = tid >> 4, cc = (tid & 15) * 4;
        float4 qa = *(const float4*)&q0[((size_t)b * N_ + n0 + rr) * 64 + cc];
        sq[rr][cc] = qa.x; sq[rr][cc + 1] = qa.y; sq[rr][cc + 2] = qa.z; sq[rr][cc + 3] = qa.w;
        float4 ka = *(const float4*)&k0[((size_t)b * N_ + m0 + rr) * 64 + cc];
        sk[rr][cc] = ka.x; sk[rr][cc + 1] = ka.y; sk[rr][cc + 2] = ka.z; sk[rr][cc + 3] = ka.w;
    }
    __syncthreads();
    float acc = 0.f;
#pragma unroll 8
    for (int d = 0; d < 64; ++d) acc += sq[ty][d] * sk[tx][d];
    float val;
    if (m < n && m != 0) val = fmaxf(acc * 0.125f, 0.f); else val = 0.f;
    *out = val;
}

// -------------------------------- partial column sums of S rows 0..1023
__global__ __launch_bounds__(256) void p_kernel(const float* __restrict__ S,
                                                float* __restrict__ P)
{
    int b = blockIdx.z, c = blockIdx.y;
    int m = blockIdx.x * 256 + threadIdx.x;
    const float* base = S + ((size_t)b * N_ + c * 128) * M_ + m;
    float s = 0.f;
    for (int j = 0; j < 128; ++j) s += base[(size_t)j * M_];
    P[((size_t)b * 8 + c) * M_ + m] = s;
}

// --------------------------------------------- sequential greedy eviction
// Single wave per batch. Lane t owns columns m = j*256 + t*4 + c (j<8,c<4).
// Evicted column -> cum = -1e30 (absorbing under += rr, rr >= 0; monotone
// u32 key maps it below every non-negative). Columns m >= i sit at exactly
// 0 and never win (col 0 is a permanent 0-valued candidate with smaller m).
// Tournament tree with >=-keep-left == first-max == jnp.argmax semantics.
__global__ __launch_bounds__(64, 1) void evict_kernel(
    const float* __restrict__ S, const float* __restrict__ P,
    int* __restrict__ evt)
{
    int b = blockIdx.x, t = threadIdx.x;
    const float* Sb = S + (size_t)b * N_ * M_;

    floatx4 cum[8];
#pragma unroll
    for (int j = 0; j < 8; ++j) {
        floatx4 s4 = {0.f, 0.f, 0.f, 0.f};
#pragma unroll
        for (int ch = 0; ch < 8; ++ch)
            s4 = s4 + *(const floatx4*)&P[((size_t)b * 8 + ch) * M_ + j * 256 + t * 4];
        cum[j] = s4;
        int4 init = {0x3FFFFFFF, 0x3FFFFFFF, 0x3FFFFFFF, 0x3FFFFFFF};
        *(int4*)&evt[b * M_ + j * 256 + t * 4] = init;
    }
    floatx4 rr[8];
#pragma unroll
    for (int j = 0; j < 8; ++j)
        rr[j] = *(const floatx4*)&Sb[(size_t)BUD_ * M_ + j * 256 + t * 4];

    for (int i = BUD_; i < M_; ++i) {
        // ---- local argmax over the 32 owned columns (tie -> min index) ----
        float va[16]; int ea[16];
#pragma unroll
        for (int k = 0; k < 16; ++k) {
            float a = cum[k >> 1][(k & 1) * 2], bb = cum[k >> 1][(k & 1) * 2 + 1];
            bool left = a >= bb;
            va[k] = left ? a : bb;
            ea[k] = left ? 2 * k : 2 * k + 1;
        }
#pragma unroll
        for (int w = 8; w >= 1; w >>= 1)
#pragma unroll
            for (int k = 0; k < w; ++k) {
                bool left = va[2 * k] >= va[2 * k + 1];
                va[k] = left ? va[2 * k] : va[2 * k + 1];
                ea[k] = left ? ea[2 * k] : ea[2 * k + 1];
            }
        int bestm = ((ea[0] >> 2) << 8) | (t << 2) | (ea[0] & 3);
        // monotone float->u32 key (relu scores >= 0, sentinel -1e30 maps low)
        u32 bits = __float_as_uint(va[0]);
        u32 key = bits ^ (((u32)((int)bits >> 31)) | 0x80000000u);
        u64 pk = ((u64)key << 32) | (u32)(2048 - bestm);     // tie -> min m
#pragma unroll
        for (int d = 1; d < 64; d <<= 1) {
            u64 o = __shfl_xor(pk, d);
            if (o > pk) pk = o;
        }
        int mstar = 2048 - (int)(pk & 0xFFFFFFFFu);
        if (((mstar >> 2) & 63) == t) evt[b * M_ + mstar] = i;

        // ---- cum += S[i]; evicted column -> sentinel ----
#pragma unroll
        for (int j = 0; j < 8; ++j) {
            floatx4 nv = cum[j] + rr[j];
            int base = (j << 8) | (t << 2);
#pragma unroll
            for (int c = 0; c < 4; ++c)
                nv[c] = (mstar == (base | c)) ? -1e30f : nv[c];
            cum[j] = nv;
        }
        // ---- prefetch row i+1 (clamped; consumed next iteration) ----
        int nr = i + 1 < 2048 ? i + 1 : 2047;
#pragma unroll
        for (int j = 0; j < 8; ++j)
            rr[j] = *(const floatx4*)&Sb[(size_t)nr * M_ + j * 256 + t * 4];
    }
}

// ------------------------------------------------------ flash attention
__global__ __launch_bounds__(256) void flash_kernel(
    const u16* __restrict__ Qb, const u16* __restrict__ Kb,
    const u16* __restrict__ Vb, const int* __restrict__ evt,
    u16* __restrict__ Ob)
{
    int bh = blockIdx.y;
    int b = bh >> 4, h = bh & 15;
    int q0 = blockIdx.x * 64;
    int tid = threadIdx.x, lane = tid & 63, w = tid >> 6;
    int quad = lane >> 4, l16 = lane & 15;
    const u16* Qh = Qb + (size_t)bh * N_ * DH_;
    const u16* Kh = Kb + (size_t)bh * N_ * DH_;
    const u16* Vh = Vb + (size_t)bh * N_ * DH_;
    __shared__ __align__(16) u16 sK[64 * 64];
    __shared__ __align__(16) u16 sV[64 * 64];     // transposed [dh][key]
    __shared__ __align__(16) u16 sP[4][16 * 64];  // wave-private P
    __shared__ int sevt[64];

    short8 aq0 = *(const short8*)&Qh[(size_t)(q0 + w * 16 + l16) * 64 + quad * 8];
    short8 aq1 = *(const short8*)&Qh[(size_t)(q0 + w * 16 + l16) * 64 + quad * 8 + 32];

    floatx4 zero = {0.f, 0.f, 0.f, 0.f};
    floatx4 accO[4];
#pragma unroll
    for (int d = 0; d < 4; ++d) accO[d] = zero;
    float m_i[4] = {-1e30f, -1e30f, -1e30f, -1e30f};
    float l_i[4] = {0.f, 0.f, 0.f, 0.f};

    int ktiles = blockIdx.x + 1;
    for (int kt = 0; kt < ktiles; ++kt) {
        int k0 = kt * 64;
#pragma unroll
        for (int it = 0; it < 2; ++it) {
            int e = (tid + it * 256) * 8;
            int r = e >> 6, c = e & 63;
            *(uint4*)&sK[e] = *(const uint4*)&Kh[(size_t)(k0 + r) * 64 + c];
            uint4 vv = *(const uint4*)&Vh[(size_t)(k0 + r) * 64 + c];
            sV[(c + 0) * 64 + r] = (u16)(vv.x & 0xFFFF);
            sV[(c + 1) * 64 + r] = (u16)(vv.x >> 16);
            sV[(c + 2) * 64 + r] = (u16)(vv.y & 0xFFFF);
            sV[(c + 3) * 64 + r] = (u16)(vv.y >> 16);
            sV[(c + 4) * 64 + r] = (u16)(vv.z & 0xFFFF);
            sV[(c + 5) * 64 + r] = (u16)(vv.z >> 16);
            sV[(c + 6) * 64 + r] = (u16)(vv.w & 0xFFFF);
            sV[(c + 7) * 64 + r] = (u16)(vv.w >> 16);
        }
        if (tid < 64) sevt[tid] = evt[b * M_ + k0 + tid];
        __syncthreads();

        floatx4 lg[4];
        int nbase = q0 + w * 16 + quad * 4;
#pragma unroll
        for (int s = 0; s < 4; ++s) {
            floatx4 sc = zero;
            short8 bk0 = *(const short8*)&sK[(s * 16 + l16) * 64 + quad * 8];
            short8 bk1 = *(const short8*)&sK[(s * 16 + l16) * 64 + quad * 8 + 32];
            sc = __builtin_amdgcn_mfma_f32_16x16x32_bf16(aq0, bk0, sc, 0, 0, 0);
            sc = __builtin_amdgcn_mfma_f32_16x16x32_bf16(aq1, bk1, sc, 0, 0, 0);
            int m = k0 + s * 16 + l16;
            int ev = sevt[s * 16 + l16];
#pragma unroll
            for (int r = 0; r < 4; ++r) {
                int n = nbase + r;
                bool keep = (m <= n) && (n < ev);
                lg[s][r] = keep ? sc[r] * 0.125f : -1e30f;
            }
        }
        float mnew[4], scale[4], rs[4];
#pragma unroll
        for (int r = 0; r < 4; ++r) {
            float mx = fmaxf(fmaxf(lg[0][r], lg[1][r]), fmaxf(lg[2][r], lg[3][r]));
#pragma unroll
            for (int d = 1; d < 16; d <<= 1) mx = fmaxf(mx, __shfl_xor(mx, d));
            mnew[r] = fmaxf(m_i[r], mx);
            scale[r] = __expf(m_i[r] - mnew[r]);
            m_i[r] = mnew[r];
            rs[r] = 0.f;
        }
#pragma unroll
        for (int s = 0; s < 4; ++s)
#pragma unroll
            for (int r = 0; r < 4; ++r) {
                float p = __expf(lg[s][r] - mnew[r]);
                rs[r] += p;
                sP[w][(quad * 4 + r) * 64 + s * 16 + l16] = f2b(p);
            }
#pragma unroll
        for (int r = 0; r < 4; ++r) {
            float t_ = rs[r];
#pragma unroll
            for (int d = 1; d < 16; d <<= 1) t_ += __shfl_xor(t_, d);
            l_i[r] = l_i[r] * scale[r] + t_;
        }
#pragma unroll
        for (int dd = 0; dd < 4; ++dd) {
            accO[dd][0] *= scale[0]; accO[dd][1] *= scale[1];
            accO[dd][2] *= scale[2]; accO[dd][3] *= scale[3];
        }
        short8 ap0 = *(const short8*)&sP[w][l16 * 64 + quad * 8];
        short8 ap1 = *(const short8*)&sP[w][l16 * 64 + quad * 8 + 32];
#pragma unroll
        for (int dd = 0; dd < 4; ++dd) {
            short8 bv0 = *(const short8*)&sV[(dd * 16 + l16) * 64 + quad * 8];
            short8 bv1 = *(const short8*)&sV[(dd * 16 + l16) * 64 + quad * 8 + 32];
            accO[dd] = __builtin_amdgcn_mfma_f32_16x16x32_bf16(ap0, bv0, accO[dd], 0, 0, 0);
            accO[dd] = __builtin_amdgcn_mfma_f32_16x16x32_bf16(ap1, bv1, accO[dd], 0, 0, 0);
        }
        __syncthreads();
    }
#pragma unroll
    for (int dd = 0; dd < 4; ++dd)
#pragma unroll
        for (int r = 0; r < 4; ++r) {
            int n = q0 + w * 16 + quad * 4 + r;
            int col = h * 64 + dd * 16 + l16;
            Ob[((size_t)b * N_ + n) * D_ + col] = f2b(accO[dd][r] / l_i[r]);
        }
}

// ---------------------------------------------------------------- launch
extern "C" void kernel_launch(void* const* d_in, const int* in_sizes, int n_in,
                              void* d_out, int out_size, void* d_ws, size_t ws_size,
                              hipStream_t stream)
{
    (void)in_sizes; (void)n_in; (void)out_size; (void)ws_size;
    const float* X  = (const float*)d_in[0];
    const float* Wq = (const float*)d_in[1];
    const float* Wk = (const float*)d_in[2];
    const float* Wv = (const float*)d_in[3];
    const float* Wo = (const float*)d_in[4];
    const float* gq = (const float*)d_in[5];
    const float* bq = (const float*)d_in[6];
    const float* gk = (const float*)d_in[7];
    const float* bk = (const float*)d_in[8];

    char* p = (char*)d_ws;
    const size_t SZ_XH = (size_t)ROWS_ * D_ * 2;
    const size_t SZ_W  = (size_t)D_ * D_ * 2;
    const size_t SZ_Y  = (size_t)ROWS_ * D_ * 4;
    const size_t SZ_PK = (size_t)ROWS_ * D_ * 2;
    const size_t SZ_H0 = (size_t)ROWS_ * 64 * 4;

    size_t o = 0;
    u16* Xhi = (u16*)(p + o); o += SZ_XH;
    u16* Xlo = (u16*)(p + o); o += SZ_XH;
    u16* Wqh = (u16*)(p + o); o += SZ_W;
    u16* Wql = (u16*)(p + o); o += SZ_W;
    u16* Wkh = (u16*)(p + o); o += SZ_W;
    u16* Wkl = (u16*)(p + o); o += SZ_W;
    u16* Wvh = (u16*)(p + o); o += SZ_W;
    u16* Woh = (u16*)(p + o); o += SZ_W;
    float* Yq = (float*)(p + o); size_t oYq = o; o += SZ_Y;
    float* Yk = (float*)(p + o); o += SZ_Y;
    float* Yv = (float*)(p + o); o += SZ_Y;
    u16* Qb = (u16*)(p + o); o += SZ_PK;
    u16* Kb = (u16*)(p + o); o += SZ_PK;
    u16* Vb = (u16*)(p + o); o += SZ_PK;
    float* q0s = (float*)(p + o); o += SZ_H0;
    float* k0s = (float*)(p + o); o += SZ_H0;
    float* Pp  = (float*)(p + o); o += (size_t)B_ * 8 * M_ * 4;
    int* evt   = (int*)(p + o);  o += (size_t)B_ * M_ * 4;
    float* S = (float*)(p + oYq);   // overlay over Yq+Yk (dead after LN)
    u16* Ob  = Xhi;                 // overlay over Xhi (dead after X-GEMMs)

    cast_x_kernel<<<ROWS_ * D_ / (256 * 4), 256, 0, stream>>>(X, Xhi, Xlo);
    dim3 wgrid(32, 32), wblk(32, 32);
    cast_w_kernel<<<wgrid, wblk, 0, stream>>>(Wq, Wqh, Wql, 1);
    cast_w_kernel<<<wgrid, wblk, 0, stream>>>(Wk, Wkh, Wkl, 1);
    cast_w_kernel<<<wgrid, wblk, 0, stream>>>(Wv, Wvh, nullptr, 0);
    cast_w_kernel<<<wgrid, wblk, 0, stream>>>(Wo, Woh, nullptr, 0);

    dim3 ggrid(D_ / 128, ROWS_ / 128);
    gemm_kernel<<<ggrid, 256, 0, stream>>>(Xhi, Xlo, Wqh, Wql, 1, Yq);
    gemm_kernel<<<ggrid, 256, 0, stream>>>(Xhi, Xlo, Wkh, Wkl, 1, Yk);
    gemm_kernel<<<ggrid, 256, 0, stream>>>(Xhi, nullptr, Wvh, nullptr, 0, Yv);

    lnpack_kernel<<<ROWS_, 256, 0, stream>>>(Yq, gq, bq, Qb, q0s, 1);
    lnpack_kernel<<<ROWS_, 256, 0, stream>>>(Yk, gk, bk, Kb, k0s, 1);
    lnpack_kernel<<<ROWS_, 256, 0, stream>>>(Yv, nullptr, nullptr, Vb, nullptr, 0);

    s_kernel<<<dim3(M_ / 16, N_ / 16, B_), dim3(16, 16), 0, stream>>>(q0s, k0s, S);
    p_kernel<<<dim3(M_ / 256, 8, B_), 256, 0, stream>>>(S, Pp);
    evict_kernel<<<B_, 64, 0, stream>>>(S, Pp, evt);

    flash_kernel<<<dim3(N_ / 64, B_ * H_), 256, 0, stream>>>(Qb, Kb, Vb, evt, Ob);
    gemm_kernel<<<ggrid, 256, 0, stream>>>(Ob, nullptr, Woh, nullptr, 0, (float*)d_out);
}

// Round 4
// 1658.096 us; speedup vs baseline: 1.4832x; 1.4520x over previous
//
// MultiheadSelectiveAttentionWithTokenPruning — MI355X round 3
//
// Round-3 change: evict_kernel redesigned to FIT IN 64 VGPRs (rounds 2/3
// spilled: persistent cum[8]+rr[8] = 64 VGPRs left zero headroom for the
// tournament temps -> scratch traffic ~3500 cyc/iter). Now:
//  - S-row prefetch goes to LDS via __builtin_amdgcn_global_load_lds
//    (ping-pong 2x8KB, zero VGPR cost), consumed with ds_read_b128 after a
//    single inline-asm s_waitcnt vmcnt(0) (no __syncthreads anywhere).
//  - local argmax = fmax tree (~5 temps) + downward equality scan (1 acc,
//    exact: fmaxf returns an input bitwise) + u64 pack + 6-level butterfly
//    (same exact jnp.argmax-first-max tie semantics as before).
//  Peak live ~58 VGPRs -> no spill even under a 64-reg cap.
//
// Pipeline:
//  1  cast_x      : X fp32 -> Xhi/Xlo bf16 (split for bf16x3 GEMM)
//  2  cast_w x4   : W fp32 -> W^T bf16 (hi[+lo for Wq/Wk])
//  3  gemm split  : Yq = X@Wq  (hi*hi + hi*lo + lo*hi)  ~fp32 accuracy
//  4  gemm split  : Yk = X@Wk
//  5  gemm        : Yv = X@Wv  (plain bf16)
//  6-8 lnpack     : LN + pack to (B,H,N,Dh) bf16, head-0 fp32 copies
//  9  s_kernel    : S[b,n,m] = relu(q0.k0/8), causal/diag/col0-zeroed
// 10  p_kernel    : column partial sums of S rows 0..1023
// 11  evict       : 1024 sequential argmax evictions (single wave/batch)
// 12  flash       : all 16 heads, online softmax, mask = causal && n<evt[m]
// 13  gemm        : out = Ob @ Wo -> d_out fp32

#include <hip/hip_runtime.h>

#define B_    2
#define N_    2048
#define D_    1024
#define H_    16
#define DH_   64
#define M_    2048
#define ROWS_ 4096
#define BUD_  1024

typedef unsigned short u16;
typedef unsigned int   u32;
typedef unsigned long long u64;
typedef __attribute__((ext_vector_type(8))) short short8;
typedef __attribute__((ext_vector_type(4))) float floatx4;

__device__ __forceinline__ u16 f2b(float f) {
    u32 u = __float_as_uint(f);
    return (u16)((u + 0x7FFFu + ((u >> 16) & 1u)) >> 16);   // RNE
}
__device__ __forceinline__ float b2f(u16 h) {
    return __uint_as_float(((u32)h) << 16);
}

// ---------------------------------------------------------------- cast X
__global__ __launch_bounds__(256) void cast_x_kernel(
    const float* __restrict__ X, u16* __restrict__ Xhi, u16* __restrict__ Xlo)
{
    int idx = (blockIdx.x * 256 + threadIdx.x) * 4;
    float4 v = *(const float4*)&X[idx];
    u16 h0 = f2b(v.x), h1 = f2b(v.y), h2 = f2b(v.z), h3 = f2b(v.w);
    ushort4 hv; hv.x = h0; hv.y = h1; hv.z = h2; hv.w = h3;
    *(ushort4*)&Xhi[idx] = hv;
    ushort4 lv;
    lv.x = f2b(v.x - b2f(h0)); lv.y = f2b(v.y - b2f(h1));
    lv.z = f2b(v.z - b2f(h2)); lv.w = f2b(v.w - b2f(h3));
    *(ushort4*)&Xlo[idx] = lv;
}

// ------------------------------------------------- cast + transpose W
__global__ __launch_bounds__(1024) void cast_w_kernel(
    const float* __restrict__ W, u16* __restrict__ Whi, u16* __restrict__ Wlo,
    int do_lo)
{
    __shared__ float tile[32][33];
    int tx = threadIdx.x, ty = threadIdx.y;
    int x = blockIdx.x * 32 + tx, y = blockIdx.y * 32 + ty;
    tile[ty][tx] = W[(size_t)y * D_ + x];
    __syncthreads();
    float v = tile[tx][ty];
    int n = blockIdx.x * 32 + ty, k = blockIdx.y * 32 + tx;
    u16 h = f2b(v);
    Whi[(size_t)n * D_ + k] = h;
    if (do_lo) Wlo[(size_t)n * D_ + k] = f2b(v - b2f(h));
}

// ------------------------------------------------------------- GEMM
// C[4096][1024] = A[4096][1024] @ Bt^T   (Bt stored [n][k])
// mode 1: C = Ah*Bh + Ah*Bl + Al*Bh  (bf16x3 split, ~fp32 precision)
__global__ __launch_bounds__(256) void gemm_kernel(
    const u16* __restrict__ Ah, const u16* __restrict__ Al,
    const u16* __restrict__ Bh, const u16* __restrict__ Bl,
    int mode, float* __restrict__ C)
{
    __shared__ __align__(16) u16 sAh[128 * 32];
    __shared__ __align__(16) u16 sBh[128 * 32];
    __shared__ __align__(16) u16 sAl[128 * 32];
    __shared__ __align__(16) u16 sBl[128 * 32];
    int tid = threadIdx.x;
    int lane = tid & 63, wv = tid >> 6;
    int wr = wv >> 1, wc = wv & 1;
    int quad = lane >> 4, l16 = lane & 15;
    int m0 = blockIdx.y * 128, n0 = blockIdx.x * 128;

    floatx4 acc[4][4];
    floatx4 zero = {0.f, 0.f, 0.f, 0.f};
#pragma unroll
    for (int i = 0; i < 4; ++i)
#pragma unroll
        for (int j = 0; j < 4; ++j) acc[i][j] = zero;

    for (int k0 = 0; k0 < 1024; k0 += 32) {
#pragma unroll
        for (int it = 0; it < 2; ++it) {
            int e = (tid + it * 256) * 8;
            int r = e >> 5, c = e & 31;
            *(uint4*)&sAh[e] = *(const uint4*)&Ah[(size_t)(m0 + r) * 1024 + k0 + c];
            *(uint4*)&sBh[e] = *(const uint4*)&Bh[(size_t)(n0 + r) * 1024 + k0 + c];
            if (mode) {
                *(uint4*)&sAl[e] = *(const uint4*)&Al[(size_t)(m0 + r) * 1024 + k0 + c];
                *(uint4*)&sBl[e] = *(const uint4*)&Bl[(size_t)(n0 + r) * 1024 + k0 + c];
            }
        }
        __syncthreads();
        short8 ah[4], al[4], bh[4], bl[4];
#pragma unroll
        for (int x = 0; x < 4; ++x) {
            int ra = (wr * 64 + x * 16 + l16) * 32 + quad * 8;
            int rb = (wc * 64 + x * 16 + l16) * 32 + quad * 8;
            ah[x] = *(const short8*)&sAh[ra];
            bh[x] = *(const short8*)&sBh[rb];
            if (mode) {
                al[x] = *(const short8*)&sAl[ra];
                bl[x] = *(const short8*)&sBl[rb];
            }
        }
#pragma unroll
        for (int mi = 0; mi < 4; ++mi)
#pragma unroll
            for (int ni = 0; ni < 4; ++ni) {
                acc[mi][ni] = __builtin_amdgcn_mfma_f32_16x16x32_bf16(
                    ah[mi], bh[ni], acc[mi][ni], 0, 0, 0);
                if (mode) {
                    acc[mi][ni] = __builtin_amdgcn_mfma_f32_16x16x32_bf16(
                        ah[mi], bl[ni], acc[mi][ni], 0, 0, 0);
                    acc[mi][ni] = __builtin_amdgcn_mfma_f32_16x16x32_bf16(
                        al[mi], bh[ni], acc[mi][ni], 0, 0, 0);
                }
            }
        __syncthreads();
    }
    // C/D layout: col = lane&15, row = (lane>>4)*4 + reg   [verified m89/m91]
#pragma unroll
    for (int mi = 0; mi < 4; ++mi)
#pragma unroll
        for (int ni = 0; ni < 4; ++ni)
#pragma unroll
            for (int r = 0; r < 4; ++r) {
                int row = m0 + wr * 64 + mi * 16 + quad * 4 + r;
                int col = n0 + wc * 64 + ni * 16 + l16;
                C[(size_t)row * 1024 + col] = acc[mi][ni][r];
            }
}

// ----------------------------------------------------- LayerNorm + pack
__global__ __launch_bounds__(256) void lnpack_kernel(
    const float* __restrict__ Y, const float* __restrict__ gamma,
    const float* __restrict__ beta, u16* __restrict__ Pk,
    float* __restrict__ head0, int do_ln)
{
    int r = blockIdx.x;
    int tid = threadIdx.x;
    float4 v = *(const float4*)&Y[(size_t)r * D_ + tid * 4];
    float mu = 0.f, rsig = 1.f;
    __shared__ float sS[4], sQ[4];
    if (do_ln) {
        float s = v.x + v.y + v.z + v.w;
        float q = v.x * v.x + v.y * v.y + v.z * v.z + v.w * v.w;
#pragma unroll
        for (int d = 1; d < 64; d <<= 1) { s += __shfl_xor(s, d); q += __shfl_xor(q, d); }
        if ((tid & 63) == 0) { sS[tid >> 6] = s; sQ[tid >> 6] = q; }
        __syncthreads();
        s = sS[0] + sS[1] + sS[2] + sS[3];
        q = sQ[0] + sQ[1] + sQ[2] + sQ[3];
        mu = s * (1.f / 1024.f);
        float var = q * (1.f / 1024.f) - mu * mu;
        rsig = rsqrtf(var + 1e-5f);
    }
    int b = r >> 11, n = r & 2047;
    float xs[4] = {v.x, v.y, v.z, v.w};
#pragma unroll
    for (int j = 0; j < 4; ++j) {
        int c = tid * 4 + j;
        float val = do_ln ? ((xs[j] - mu) * rsig * gamma[c] + beta[c]) : xs[j];
        int h = c >> 6, dh = c & 63;
        Pk[(((size_t)b * H_ + h) * N_ + n) * DH_ + dh] = f2b(val);
        if (head0 && c < 64) head0[(size_t)r * 64 + c] = val;
    }
}

// -------------------------------------------- head-0 selection scores S
__global__ void s_kernel(const float* __restrict__ q0,
                         const float* __restrict__ k0, float* __restrict__ S)
{
    int b = blockIdx.z;
    int n0 = blockIdx.y * 16, m0 = blockIdx.x * 16;
    int tx = threadIdx.x, ty = threadIdx.y;
    int n = n0 + ty, m = m0 + tx;
    float* out = S + ((size_t)b * N_ + n) * M_ + m;
    if (m0 > n0 + 15) { *out = 0.f; return; }   // fully above diagonal
    __shared__ float sq[16][65], sk[16][65];
    int tid = ty * 16 + tx;
    {
        int rr = tid >> 4, cc = (tid & 15) * 4;
        float4 qa = *(const float4*)&q0[((size_t)b * N_ + n0 + rr) * 64 + cc];
        sq[rr][cc] = qa.x; sq[rr][cc + 1] = qa.y; sq[rr][cc + 2] = qa.z; sq[rr][cc + 3] = qa.w;
        float4 ka = *(const float4*)&k0[((size_t)b * N_ + m0 + rr) * 64 + cc];
        sk[rr][cc] = ka.x; sk[rr][cc + 1] = ka.y; sk[rr][cc + 2] = ka.z; sk[rr][cc + 3] = ka.w;
    }
    __syncthreads();
    float acc = 0.f;
#pragma unroll 8
    for (int d = 0; d < 64; ++d) acc += sq[ty][d] * sk[tx][d];
    float val;
    if (m < n && m != 0) val = fmaxf(acc * 0.125f, 0.f); else val = 0.f;
    *out = val;
}

// -------------------------------- partial column sums of S rows 0..1023
__global__ __launch_bounds__(256) void p_kernel(const float* __restrict__ S,
                                                float* __restrict__ P)
{
    int b = blockIdx.z, c = blockIdx.y;
    int m = blockIdx.x * 256 + threadIdx.x;
    const float* base = S + ((size_t)b * N_ + c * 128) * M_ + m;
    float s = 0.f;
    for (int j = 0; j < 128; ++j) s += base[(size_t)j * M_];
    P[((size_t)b * 8 + c) * M_ + m] = s;
}

// --------------------------------------------- sequential greedy eviction
// Single wave per batch. Lane t owns columns m = j*256 + t*4 + c (j<8,c<4),
// element e = j*4+c (ascending e == ascending m). Evicted column -> cum =
// -1e30 (absorbing, rr >= 0). Columns m >= i sit at exactly 0 and never win
// (col 0 is a permanent 0-valued candidate with smaller m). Local argmax:
// fmax tree (bitwise-exact: fmaxf returns an input) + downward first-equal
// scan; global: u64 (monotone-key, 2048-m) butterfly max == jnp.argmax.
// S rows prefetched into LDS ping-pong buffers via global_load_lds (zero
// VGPR cost); single inline s_waitcnt vmcnt(0) per iter, no barriers.
__global__ __launch_bounds__(64) void evict_kernel(
    const float* __restrict__ S, const float* __restrict__ P,
    int* __restrict__ evt)
{
    __shared__ __align__(16) float lrow[2][2048];   // 16 KiB ping-pong
    int b = blockIdx.x, t = threadIdx.x;
    const float* Sb = S + (size_t)b * N_ * M_;

    // prefetch row 1024 into buffer 0 (8 x 1KB wave-wide async copies)
#pragma unroll
    for (int seg = 0; seg < 8; ++seg)
        __builtin_amdgcn_global_load_lds(
            (const __attribute__((address_space(1))) void*)
                (Sb + (size_t)BUD_ * M_ + seg * 256 + t * 4),
            (__attribute__((address_space(3))) void*)&lrow[0][seg * 256],
            16, 0, 0);

    floatx4 cum[8];
#pragma unroll
    for (int j = 0; j < 8; ++j) {
        floatx4 s4 = {0.f, 0.f, 0.f, 0.f};
#pragma unroll
        for (int ch = 0; ch < 8; ++ch)
            s4 = s4 + *(const floatx4*)&P[((size_t)b * 8 + ch) * M_ + j * 256 + t * 4];
        cum[j] = s4;
        int4 init = {0x3FFFFFFF, 0x3FFFFFFF, 0x3FFFFFFF, 0x3FFFFFFF};
        *(int4*)&evt[b * M_ + j * 256 + t * 4] = init;
    }

    for (int i = BUD_; i < M_; ++i) {
        // ---- local max over 32 owned columns (fmax tree, few temps) ----
        float mx = -1e30f;
#pragma unroll
        for (int j = 0; j < 8; ++j) {
            float a = fmaxf(fmaxf(cum[j][0], cum[j][1]),
                            fmaxf(cum[j][2], cum[j][3]));
            mx = fmaxf(mx, a);
        }
        // ---- first (min-e) element equal to mx: downward scan, 1 acc ----
        int be = 0;
#pragma unroll
        for (int e = 31; e >= 0; --e)
            be = (cum[e >> 2][e & 3] == mx) ? e : be;
        int bestm = ((be >> 2) << 8) | (t << 2) | (be & 3);
        // monotone float->u32 key (handles -1e30 sentinel sign bit)
        u32 bits = __float_as_uint(mx);
        u32 key = bits ^ (((u32)((int)bits >> 31)) | 0x80000000u);
        u64 pk = ((u64)key << 32) | (u32)(2048 - bestm);     // tie -> min m
#pragma unroll
        for (int d = 1; d < 64; d <<= 1) {
            u64 o = __shfl_xor(pk, d);
            if (o > pk) pk = o;
        }
        int mstar = 2048 - (int)(pk & 0xFFFFFFFFu);
        if (((mstar >> 2) & 63) == t) evt[b * M_ + mstar] = i;

        // ---- row i is resident after draining the async copies ----
        asm volatile("s_waitcnt vmcnt(0)" ::: "memory");
        // issue prefetch of row i+1 into the other buffer (clamped)
        {
            size_t nr = (size_t)(i + 1 < 2048 ? i + 1 : 2047);
            int nb = (i + 1) & 1;
#pragma unroll
            for (int seg = 0; seg < 8; ++seg)
                __builtin_amdgcn_global_load_lds(
                    (const __attribute__((address_space(1))) void*)
                        (Sb + nr * M_ + seg * 256 + t * 4),
                    (__attribute__((address_space(3))) void*)&lrow[nb][seg * 256],
                    16, 0, 0);
        }
        // ---- cum += row_i; evicted column -> sentinel ----
        int cb = i & 1;
        int ec = mstar - (t << 2);   // matches (j<<8)|c for the owned column
#pragma unroll
        for (int j = 0; j < 8; ++j) {
            floatx4 rr = *(const floatx4*)&lrow[cb][j * 256 + t * 4];
            floatx4 nv = cum[j] + rr;
#pragma unroll
            for (int c = 0; c < 4; ++c)
                nv[c] = (ec == ((j << 8) | c)) ? -1e30f : nv[c];
            cum[j] = nv;
        }
    }
}

// ------------------------------------------------------ flash attention
__global__ __launch_bounds__(256) void flash_kernel(
    const u16* __restrict__ Qb, const u16* __restrict__ Kb,
    const u16* __restrict__ Vb, const int* __restrict__ evt,
    u16* __restrict__ Ob)
{
    int bh = blockIdx.y;
    int b = bh >> 4, h = bh & 15;
    int q0 = blockIdx.x * 64;
    int tid = threadIdx.x, lane = tid & 63, w = tid >> 6;
    int quad = lane >> 4, l16 = lane & 15;
    const u16* Qh = Qb + (size_t)bh * N_ * DH_;
    const u16* Kh = Kb + (size_t)bh * N_ * DH_;
    const u16* Vh = Vb + (size_t)bh * N_ * DH_;
    __shared__ __align__(16) u16 sK[64 * 64];
    __shared__ __align__(16) u16 sV[64 * 64];     // transposed [dh][key]
    __shared__ __align__(16) u16 sP[4][16 * 64];  // wave-private P
    __shared__ int sevt[64];

    short8 aq0 = *(const short8*)&Qh[(size_t)(q0 + w * 16 + l16) * 64 + quad * 8];
    short8 aq1 = *(const short8*)&Qh[(size_t)(q0 + w * 16 + l16) * 64 + quad * 8 + 32];

    floatx4 zero = {0.f, 0.f, 0.f, 0.f};
    floatx4 accO[4];
#pragma unroll
    for (int d = 0; d < 4; ++d) accO[d] = zero;
    float m_i[4] = {-1e30f, -1e30f, -1e30f, -1e30f};
    float l_i[4] = {0.f, 0.f, 0.f, 0.f};

    int ktiles = blockIdx.x + 1;
    for (int kt = 0; kt < ktiles; ++kt) {
        int k0 = kt * 64;
#pragma unroll
        for (int it = 0; it < 2; ++it) {
            int e = (tid + it * 256) * 8;
            int r = e >> 6, c = e & 63;
            *(uint4*)&sK[e] = *(const uint4*)&Kh[(size_t)(k0 + r) * 64 + c];
            uint4 vv = *(const uint4*)&Vh[(size_t)(k0 + r) * 64 + c];
            sV[(c + 0) * 64 + r] = (u16)(vv.x & 0xFFFF);
            sV[(c + 1) * 64 + r] = (u16)(vv.x >> 16);
            sV[(c + 2) * 64 + r] = (u16)(vv.y & 0xFFFF);
            sV[(c + 3) * 64 + r] = (u16)(vv.y >> 16);
            sV[(c + 4) * 64 + r] = (u16)(vv.z & 0xFFFF);
            sV[(c + 5) * 64 + r] = (u16)(vv.z >> 16);
            sV[(c + 6) * 64 + r] = (u16)(vv.w & 0xFFFF);
            sV[(c + 7) * 64 + r] = (u16)(vv.w >> 16);
        }
        if (tid < 64) sevt[tid] = evt[b * M_ + k0 + tid];
        __syncthreads();

        floatx4 lg[4];
        int nbase = q0 + w * 16 + quad * 4;
#pragma unroll
        for (int s = 0; s < 4; ++s) {
            floatx4 sc = zero;
            short8 bk0 = *(const short8*)&sK[(s * 16 + l16) * 64 + quad * 8];
            short8 bk1 = *(const short8*)&sK[(s * 16 + l16) * 64 + quad * 8 + 32];
            sc = __builtin_amdgcn_mfma_f32_16x16x32_bf16(aq0, bk0, sc, 0, 0, 0);
            sc = __builtin_amdgcn_mfma_f32_16x16x32_bf16(aq1, bk1, sc, 0, 0, 0);
            int m = k0 + s * 16 + l16;
            int ev = sevt[s * 16 + l16];
#pragma unroll
            for (int r = 0; r < 4; ++r) {
                int n = nbase + r;
                bool keep = (m <= n) && (n < ev);
                lg[s][r] = keep ? sc[r] * 0.125f : -1e30f;
            }
        }
        float mnew[4], scale[4], rs[4];
#pragma unroll
        for (int r = 0; r < 4; ++r) {
            float mx = fmaxf(fmaxf(lg[0][r], lg[1][r]), fmaxf(lg[2][r], lg[3][r]));
#pragma unroll
            for (int d = 1; d < 16; d <<= 1) mx = fmaxf(mx, __shfl_xor(mx, d));
            mnew[r] = fmaxf(m_i[r], mx);
            scale[r] = __expf(m_i[r] - mnew[r]);
            m_i[r] = mnew[r];
            rs[r] = 0.f;
        }
#pragma unroll
        for (int s = 0; s < 4; ++s)
#pragma unroll
            for (int r = 0; r < 4; ++r) {
                float p = __expf(lg[s][r] - mnew[r]);
                rs[r] += p;
                sP[w][(quad * 4 + r) * 64 + s * 16 + l16] = f2b(p);
            }
#pragma unroll
        for (int r = 0; r < 4; ++r) {
            float t_ = rs[r];
#pragma unroll
            for (int d = 1; d < 16; d <<= 1) t_ += __shfl_xor(t_, d);
            l_i[r] = l_i[r] * scale[r] + t_;
        }
#pragma unroll
        for (int dd = 0; dd < 4; ++dd) {
            accO[dd][0] *= scale[0]; accO[dd][1] *= scale[1];
            accO[dd][2] *= scale[2]; accO[dd][3] *= scale[3];
        }
        short8 ap0 = *(const short8*)&sP[w][l16 * 64 + quad * 8];
        short8 ap1 = *(const short8*)&sP[w][l16 * 64 + quad * 8 + 32];
#pragma unroll
        for (int dd = 0; dd < 4; ++dd) {
            short8 bv0 = *(const short8*)&sV[(dd * 16 + l16) * 64 + quad * 8];
            short8 bv1 = *(const short8*)&sV[(dd * 16 + l16) * 64 + quad * 8 + 32];
            accO[dd] = __builtin_amdgcn_mfma_f32_16x16x32_bf16(ap0, bv0, accO[dd], 0, 0, 0);
            accO[dd] = __builtin_amdgcn_mfma_f32_16x16x32_bf16(ap1, bv1, accO[dd], 0, 0, 0);
        }
        __syncthreads();
    }
#pragma unroll
    for (int dd = 0; dd < 4; ++dd)
#pragma unroll
        for (int r = 0; r < 4; ++r) {
            int n = q0 + w * 16 + quad * 4 + r;
            int col = h * 64 + dd * 16 + l16;
            Ob[((size_t)b * N_ + n) * D_ + col] = f2b(accO[dd][r] / l_i[r]);
        }
}

// ---------------------------------------------------------------- launch
extern "C" void kernel_launch(void* const* d_in, const int* in_sizes, int n_in,
                              void* d_out, int out_size, void* d_ws, size_t ws_size,
                              hipStream_t stream)
{
    (void)in_sizes; (void)n_in; (void)out_size; (void)ws_size;
    const float* X  = (const float*)d_in[0];
    const float* Wq = (const float*)d_in[1];
    const float* Wk = (const float*)d_in[2];
    const float* Wv = (const float*)d_in[3];
    const float* Wo = (const float*)d_in[4];
    const float* gq = (const float*)d_in[5];
    const float* bq = (const float*)d_in[6];
    const float* gk = (const float*)d_in[7];
    const float* bk = (const float*)d_in[8];

    char* p = (char*)d_ws;
    const size_t SZ_XH = (size_t)ROWS_ * D_ * 2;
    const size_t SZ_W  = (size_t)D_ * D_ * 2;
    const size_t SZ_Y  = (size_t)ROWS_ * D_ * 4;
    const size_t SZ_PK = (size_t)ROWS_ * D_ * 2;
    const size_t SZ_H0 = (size_t)ROWS_ * 64 * 4;

    size_t o = 0;
    u16* Xhi = (u16*)(p + o); o += SZ_XH;
    u16* Xlo = (u16*)(p + o); o += SZ_XH;
    u16* Wqh = (u16*)(p + o); o += SZ_W;
    u16* Wql = (u16*)(p + o); o += SZ_W;
    u16* Wkh = (u16*)(p + o); o += SZ_W;
    u16* Wkl = (u16*)(p + o); o += SZ_W;
    u16* Wvh = (u16*)(p + o); o += SZ_W;
    u16* Woh = (u16*)(p + o); o += SZ_W;
    float* Yq = (float*)(p + o); size_t oYq = o; o += SZ_Y;
    float* Yk = (float*)(p + o); o += SZ_Y;
    float* Yv = (float*)(p + o); o += SZ_Y;
    u16* Qb = (u16*)(p + o); o += SZ_PK;
    u16* Kb = (u16*)(p + o); o += SZ_PK;
    u16* Vb = (u16*)(p + o); o += SZ_PK;
    float* q0s = (float*)(p + o); o += SZ_H0;
    float* k0s = (float*)(p + o); o += SZ_H0;
    float* Pp  = (float*)(p + o); o += (size_t)B_ * 8 * M_ * 4;
    int* evt   = (int*)(p + o);  o += (size_t)B_ * M_ * 4;
    float* S = (float*)(p + oYq);   // overlay over Yq+Yk (dead after LN)
    u16* Ob  = Xhi;                 // overlay over Xhi (dead after X-GEMMs)

    cast_x_kernel<<<ROWS_ * D_ / (256 * 4), 256, 0, stream>>>(X, Xhi, Xlo);
    dim3 wgrid(32, 32), wblk(32, 32);
    cast_w_kernel<<<wgrid, wblk, 0, stream>>>(Wq, Wqh, Wql, 1);
    cast_w_kernel<<<wgrid, wblk, 0, stream>>>(Wk, Wkh, Wkl, 1);
    cast_w_kernel<<<wgrid, wblk, 0, stream>>>(Wv, Wvh, nullptr, 0);
    cast_w_kernel<<<wgrid, wblk, 0, stream>>>(Wo, Woh, nullptr, 0);

    dim3 ggrid(D_ / 128, ROWS_ / 128);
    gemm_kernel<<<ggrid, 256, 0, stream>>>(Xhi, Xlo, Wqh, Wql, 1, Yq);
    gemm_kernel<<<ggrid, 256, 0, stream>>>(Xhi, Xlo, Wkh, Wkl, 1, Yk);
    gemm_kernel<<<ggrid, 256, 0, stream>>>(Xhi, nullptr, Wvh, nullptr, 0, Yv);

    lnpack_kernel<<<ROWS_, 256, 0, stream>>>(Yq, gq, bq, Qb, q0s, 1);
    lnpack_kernel<<<ROWS_, 256, 0, stream>>>(Yk, gk, bk, Kb, k0s, 1);
    lnpack_kernel<<<ROWS_, 256, 0, stream>>>(Yv, nullptr, nullptr, Vb, nullptr, 0);

    s_kernel<<<dim3(M_ / 16, N_ / 16, B_), dim3(16, 16), 0, stream>>>(q0s, k0s, S);
    p_kernel<<<dim3(M_ / 256, 8, B_), 256, 0, stream>>>(S, Pp);
    evict_kernel<<<B_, 64, 0, stream>>>(S, Pp, evt);

    flash_kernel<<<dim3(N_ / 64, B_ * H_), 256, 0, stream>>>(Qb, Kb, Vb, evt, Ob);
    gemm_kernel<<<ggrid, 256, 0, stream>>>(Ob, nullptr, Woh, nullptr, 0, (float*)d_out);
}

// Round 5
// 1539.902 us; speedup vs baseline: 1.5970x; 1.0768x over previous
//
// MultiheadSelectiveAttentionWithTokenPruning — MI355X round 4
//
// Round-4 change (evict only): kill the three per-iteration latency taxes
// found in round 3's ~2550 cyc/iter:
//  (a) u64 butterfly via __shfl_xor = 6 x ds_bpermute @ ~120cyc exposed
//      latency (single wave) -> replaced with DPP reduction (row_shr
//      1/2/4/8 + row_bcast 15/31, VALU pipe, ~20 cyc/step), result in
//      lane 63, broadcast via readlane.
//  (b) per-iter evt global STORE drained by s_waitcnt vmcnt(0) (stores
//      count in vmcnt) -> evt kept in LDS, dumped once after the loop.
//  (c) vmcnt(0) -> issue prefetch(i+1) FIRST then s_waitcnt vmcnt(8):
//      waits only row i's 8 oldest loads, never the fresh ones.
// Also: ds_read row i into temps BEFORE the argmax so the DS latency is
// hidden under the argmax VALU chain.
//
// Pipeline:
//  1  cast_x      : X fp32 -> Xhi/Xlo bf16 (split for bf16x3 GEMM)
//  2  cast_w x4   : W fp32 -> W^T bf16 (hi[+lo for Wq/Wk])
//  3  gemm split  : Yq = X@Wq  (hi*hi + hi*lo + lo*hi)  ~fp32 accuracy
//  4  gemm split  : Yk = X@Wk
//  5  gemm        : Yv = X@Wv  (plain bf16)
//  6-8 lnpack     : LN + pack to (B,H,N,Dh) bf16, head-0 fp32 copies
//  9  s_kernel    : S[b,n,m] = relu(q0.k0/8), causal/diag/col0-zeroed
// 10  p_kernel    : column partial sums of S rows 0..1023
// 11  evict       : 1024 sequential argmax evictions (single wave/batch)
// 12  flash       : all 16 heads, online softmax, mask = causal && n<evt[m]
// 13  gemm        : out = Ob @ Wo -> d_out fp32

#include <hip/hip_runtime.h>

#define B_    2
#define N_    2048
#define D_    1024
#define H_    16
#define DH_   64
#define M_    2048
#define ROWS_ 4096
#define BUD_  1024

typedef unsigned short u16;
typedef unsigned int   u32;
typedef unsigned long long u64;
typedef __attribute__((ext_vector_type(8))) short short8;
typedef __attribute__((ext_vector_type(4))) float floatx4;

__device__ __forceinline__ u16 f2b(float f) {
    u32 u = __float_as_uint(f);
    return (u16)((u + 0x7FFFu + ((u >> 16) & 1u)) >> 16);   // RNE
}
__device__ __forceinline__ float b2f(u16 h) {
    return __uint_as_float(((u32)h) << 16);
}

// ---------------------------------------------------------------- cast X
__global__ __launch_bounds__(256) void cast_x_kernel(
    const float* __restrict__ X, u16* __restrict__ Xhi, u16* __restrict__ Xlo)
{
    int idx = (blockIdx.x * 256 + threadIdx.x) * 4;
    float4 v = *(const float4*)&X[idx];
    u16 h0 = f2b(v.x), h1 = f2b(v.y), h2 = f2b(v.z), h3 = f2b(v.w);
    ushort4 hv; hv.x = h0; hv.y = h1; hv.z = h2; hv.w = h3;
    *(ushort4*)&Xhi[idx] = hv;
    ushort4 lv;
    lv.x = f2b(v.x - b2f(h0)); lv.y = f2b(v.y - b2f(h1));
    lv.z = f2b(v.z - b2f(h2)); lv.w = f2b(v.w - b2f(h3));
    *(ushort4*)&Xlo[idx] = lv;
}

// ------------------------------------------------- cast + transpose W
__global__ __launch_bounds__(1024) void cast_w_kernel(
    const float* __restrict__ W, u16* __restrict__ Whi, u16* __restrict__ Wlo,
    int do_lo)
{
    __shared__ float tile[32][33];
    int tx = threadIdx.x, ty = threadIdx.y;
    int x = blockIdx.x * 32 + tx, y = blockIdx.y * 32 + ty;
    tile[ty][tx] = W[(size_t)y * D_ + x];
    __syncthreads();
    float v = tile[tx][ty];
    int n = blockIdx.x * 32 + ty, k = blockIdx.y * 32 + tx;
    u16 h = f2b(v);
    Whi[(size_t)n * D_ + k] = h;
    if (do_lo) Wlo[(size_t)n * D_ + k] = f2b(v - b2f(h));
}

// ------------------------------------------------------------- GEMM
// C[4096][1024] = A[4096][1024] @ Bt^T   (Bt stored [n][k])
// mode 1: C = Ah*Bh + Ah*Bl + Al*Bh  (bf16x3 split, ~fp32 precision)
__global__ __launch_bounds__(256) void gemm_kernel(
    const u16* __restrict__ Ah, const u16* __restrict__ Al,
    const u16* __restrict__ Bh, const u16* __restrict__ Bl,
    int mode, float* __restrict__ C)
{
    __shared__ __align__(16) u16 sAh[128 * 32];
    __shared__ __align__(16) u16 sBh[128 * 32];
    __shared__ __align__(16) u16 sAl[128 * 32];
    __shared__ __align__(16) u16 sBl[128 * 32];
    int tid = threadIdx.x;
    int lane = tid & 63, wv = tid >> 6;
    int wr = wv >> 1, wc = wv & 1;
    int quad = lane >> 4, l16 = lane & 15;
    int m0 = blockIdx.y * 128, n0 = blockIdx.x * 128;

    floatx4 acc[4][4];
    floatx4 zero = {0.f, 0.f, 0.f, 0.f};
#pragma unroll
    for (int i = 0; i < 4; ++i)
#pragma unroll
        for (int j = 0; j < 4; ++j) acc[i][j] = zero;

    for (int k0 = 0; k0 < 1024; k0 += 32) {
#pragma unroll
        for (int it = 0; it < 2; ++it) {
            int e = (tid + it * 256) * 8;
            int r = e >> 5, c = e & 31;
            *(uint4*)&sAh[e] = *(const uint4*)&Ah[(size_t)(m0 + r) * 1024 + k0 + c];
            *(uint4*)&sBh[e] = *(const uint4*)&Bh[(size_t)(n0 + r) * 1024 + k0 + c];
            if (mode) {
                *(uint4*)&sAl[e] = *(const uint4*)&Al[(size_t)(m0 + r) * 1024 + k0 + c];
                *(uint4*)&sBl[e] = *(const uint4*)&Bl[(size_t)(n0 + r) * 1024 + k0 + c];
            }
        }
        __syncthreads();
        short8 ah[4], al[4], bh[4], bl[4];
#pragma unroll
        for (int x = 0; x < 4; ++x) {
            int ra = (wr * 64 + x * 16 + l16) * 32 + quad * 8;
            int rb = (wc * 64 + x * 16 + l16) * 32 + quad * 8;
            ah[x] = *(const short8*)&sAh[ra];
            bh[x] = *(const short8*)&sBh[rb];
            if (mode) {
                al[x] = *(const short8*)&sAl[ra];
                bl[x] = *(const short8*)&sBl[rb];
            }
        }
#pragma unroll
        for (int mi = 0; mi < 4; ++mi)
#pragma unroll
            for (int ni = 0; ni < 4; ++ni) {
                acc[mi][ni] = __builtin_amdgcn_mfma_f32_16x16x32_bf16(
                    ah[mi], bh[ni], acc[mi][ni], 0, 0, 0);
                if (mode) {
                    acc[mi][ni] = __builtin_amdgcn_mfma_f32_16x16x32_bf16(
                        ah[mi], bl[ni], acc[mi][ni], 0, 0, 0);
                    acc[mi][ni] = __builtin_amdgcn_mfma_f32_16x16x32_bf16(
                        al[mi], bh[ni], acc[mi][ni], 0, 0, 0);
                }
            }
        __syncthreads();
    }
    // C/D layout: col = lane&15, row = (lane>>4)*4 + reg   [verified m89/m91]
#pragma unroll
    for (int mi = 0; mi < 4; ++mi)
#pragma unroll
        for (int ni = 0; ni < 4; ++ni)
#pragma unroll
            for (int r = 0; r < 4; ++r) {
                int row = m0 + wr * 64 + mi * 16 + quad * 4 + r;
                int col = n0 + wc * 64 + ni * 16 + l16;
                C[(size_t)row * 1024 + col] = acc[mi][ni][r];
            }
}

// ----------------------------------------------------- LayerNorm + pack
__global__ __launch_bounds__(256) void lnpack_kernel(
    const float* __restrict__ Y, const float* __restrict__ gamma,
    const float* __restrict__ beta, u16* __restrict__ Pk,
    float* __restrict__ head0, int do_ln)
{
    int r = blockIdx.x;
    int tid = threadIdx.x;
    float4 v = *(const float4*)&Y[(size_t)r * D_ + tid * 4];
    float mu = 0.f, rsig = 1.f;
    __shared__ float sS[4], sQ[4];
    if (do_ln) {
        float s = v.x + v.y + v.z + v.w;
        float q = v.x * v.x + v.y * v.y + v.z * v.z + v.w * v.w;
#pragma unroll
        for (int d = 1; d < 64; d <<= 1) { s += __shfl_xor(s, d); q += __shfl_xor(q, d); }
        if ((tid & 63) == 0) { sS[tid >> 6] = s; sQ[tid >> 6] = q; }
        __syncthreads();
        s = sS[0] + sS[1] + sS[2] + sS[3];
        q = sQ[0] + sQ[1] + sQ[2] + sQ[3];
        mu = s * (1.f / 1024.f);
        float var = q * (1.f / 1024.f) - mu * mu;
        rsig = rsqrtf(var + 1e-5f);
    }
    int b = r >> 11, n = r & 2047;
    float xs[4] = {v.x, v.y, v.z, v.w};
#pragma unroll
    for (int j = 0; j < 4; ++j) {
        int c = tid * 4 + j;
        float val = do_ln ? ((xs[j] - mu) * rsig * gamma[c] + beta[c]) : xs[j];
        int h = c >> 6, dh = c & 63;
        Pk[(((size_t)b * H_ + h) * N_ + n) * DH_ + dh] = f2b(val);
        if (head0 && c < 64) head0[(size_t)r * 64 + c] = val;
    }
}

// -------------------------------------------- head-0 selection scores S
__global__ void s_kernel(const float* __restrict__ q0,
                         const float* __restrict__ k0, float* __restrict__ S)
{
    int b = blockIdx.z;
    int n0 = blockIdx.y * 16, m0 = blockIdx.x * 16;
    int tx = threadIdx.x, ty = threadIdx.y;
    int n = n0 + ty, m = m0 + tx;
    float* out = S + ((size_t)b * N_ + n) * M_ + m;
    if (m0 > n0 + 15) { *out = 0.f; return; }   // fully above diagonal
    __shared__ float sq[16][65], sk[16][65];
    int tid = ty * 16 + tx;
    {
        int rr = tid >> 4, cc = (tid & 15) * 4;
        float4 qa = *(const float4*)&q0[((size_t)b * N_ + n0 + rr) * 64 + cc];
        sq[rr][cc] = qa.x; sq[rr][cc + 1] = qa.y; sq[rr][cc + 2] = qa.z; sq[rr][cc + 3] = qa.w;
        float4 ka = *(const float4*)&k0[((size_t)b * N_ + m0 + rr) * 64 + cc];
        sk[rr][cc] = ka.x; sk[rr][cc + 1] = ka.y; sk[rr][cc + 2] = ka.z; sk[rr][cc + 3] = ka.w;
    }
    __syncthreads();
    float acc = 0.f;
#pragma unroll 8
    for (int d = 0; d < 64; ++d) acc += sq[ty][d] * sk[tx][d];
    float val;
    if (m < n && m != 0) val = fmaxf(acc * 0.125f, 0.f); else val = 0.f;
    *out = val;
}

// -------------------------------- partial column sums of S rows 0..1023
__global__ __launch_bounds__(256) void p_kernel(const float* __restrict__ S,
                                                float* __restrict__ P)
{
    int b = blockIdx.z, c = blockIdx.y;
    int m = blockIdx.x * 256 + threadIdx.x;
    const float* base = S + ((size_t)b * N_ + c * 128) * M_ + m;
    float s = 0.f;
    for (int j = 0; j < 128; ++j) s += base[(size_t)j * M_];
    P[((size_t)b * 8 + c) * M_ + m] = s;
}

// --------------------------------------------- sequential greedy eviction
// Single wave per batch. Lane t owns columns m = j*256 + t*4 + c (j<8,c<4).
// Evicted column -> cum = -1e30 (absorbing, rr >= 0). Columns m >= i sit at
// exactly 0 and never win (col 0 is a permanent 0-valued candidate with
// smaller m). Local argmax: fmax tree + downward first-equal scan (exact).
// Cross-lane: monotone-key u64 (key<<32 | 2048-m) max via DPP (row_shr
// 1/2/4/8 + row_bcast 15/31, result in lane 63) == jnp.argmax tie rules.
// evt lives in LDS during the loop (no vm stores); rows stream through an
// LDS ping-pong filled by global_load_lds; s_waitcnt vmcnt(8) waits only
// for the row being consumed. No barriers (single wave).
#define DPP_MAX64(CTRL)                                                     \
    do {                                                                    \
        u32 lo_ = (u32)pk, hi_ = (u32)(pk >> 32);                           \
        u32 plo_ = (u32)__builtin_amdgcn_update_dpp(                        \
            (int)lo_, (int)lo_, CTRL, 0xf, 0xf, false);                     \
        u32 phi_ = (u32)__builtin_amdgcn_update_dpp(                        \
            (int)hi_, (int)hi_, CTRL, 0xf, 0xf, false);                     \
        u64 ot_ = ((u64)phi_ << 32) | plo_;                                 \
        pk = ot_ > pk ? ot_ : pk;                                           \
    } while (0)

__global__ __launch_bounds__(64) void evict_kernel(
    const float* __restrict__ S, const float* __restrict__ P,
    int* __restrict__ evt)
{
    __shared__ __align__(16) float lrow[2][2048];   // 16 KiB ping-pong
    __shared__ __align__(16) int evt_lds[2048];     // 8 KiB
    int b = blockIdx.x, t = threadIdx.x;
    const float* Sb = S + (size_t)b * N_ * M_;

    // prefetch row 1024 into buffer 0 (8 x 1KB wave-wide async copies)
#pragma unroll
    for (int seg = 0; seg < 8; ++seg)
        __builtin_amdgcn_global_load_lds(
            (const __attribute__((address_space(1))) void*)
                (Sb + (size_t)BUD_ * M_ + seg * 256 + t * 4),
            (__attribute__((address_space(3))) void*)&lrow[0][seg * 256],
            16, 0, 0);

    floatx4 cum[8];
#pragma unroll
    for (int j = 0; j < 8; ++j) {
        floatx4 s4 = {0.f, 0.f, 0.f, 0.f};
#pragma unroll
        for (int ch = 0; ch < 8; ++ch)
            s4 = s4 + *(const floatx4*)&P[((size_t)b * 8 + ch) * M_ + j * 256 + t * 4];
        cum[j] = s4;
        int4 init = {0x3FFFFFFF, 0x3FFFFFFF, 0x3FFFFFFF, 0x3FFFFFFF};
        *(int4*)&evt_lds[j * 256 + t * 4] = init;
    }

    for (int i = BUD_; i < M_; ++i) {
        // ---- issue prefetch of row i+1 into the other buffer ----
        {
            size_t nr = (size_t)(i + 1 < 2048 ? i + 1 : 2047);
            int nb = (i + 1) & 1;
#pragma unroll
            for (int seg = 0; seg < 8; ++seg)
                __builtin_amdgcn_global_load_lds(
                    (const __attribute__((address_space(1))) void*)
                        (Sb + nr * M_ + seg * 256 + t * 4),
                    (__attribute__((address_space(3))) void*)&lrow[nb][seg * 256],
                    16, 0, 0);
        }
        // ---- wait only for row i (the 8 oldest outstanding loads) ----
        asm volatile("s_waitcnt vmcnt(8)" ::: "memory");
        // ---- start LDS reads of row i (latency hidden under argmax) ----
        int cb = i & 1;
        floatx4 rr[8];
#pragma unroll
        for (int j = 0; j < 8; ++j)
            rr[j] = *(const floatx4*)&lrow[cb][j * 256 + t * 4];

        // ---- local max over 32 owned columns (fmax tree) ----
        float mx = -1e30f;
#pragma unroll
        for (int j = 0; j < 8; ++j) {
            float a = fmaxf(fmaxf(cum[j][0], cum[j][1]),
                            fmaxf(cum[j][2], cum[j][3]));
            mx = fmaxf(mx, a);
        }
        // ---- first (min-e) element equal to mx ----
        int be = 0;
#pragma unroll
        for (int e = 31; e >= 0; --e)
            be = (cum[e >> 2][e & 3] == mx) ? e : be;
        int bestm = ((be >> 2) << 8) | (t << 2) | (be & 3);
        // monotone float->u32 key (handles -1e30 sentinel sign bit)
        u32 bits = __float_as_uint(mx);
        u32 key = bits ^ (((u32)((int)bits >> 31)) | 0x80000000u);
        u64 pk = ((u64)key << 32) | (u32)(2048 - bestm);     // tie -> min m
        // ---- cross-lane max via DPP (VALU pipe, ~6 x 20 cyc) ----
        DPP_MAX64(0x111);   // row_shr:1
        DPP_MAX64(0x112);   // row_shr:2
        DPP_MAX64(0x114);   // row_shr:4
        DPP_MAX64(0x118);   // row_shr:8
        DPP_MAX64(0x142);   // row_bcast:15
        DPP_MAX64(0x143);   // row_bcast:31  -> lane 63 has global max
        int mlo = __builtin_amdgcn_readlane((int)(u32)(pk & 0xFFFFFFFFu), 63);
        int mstar = 2048 - mlo;
        if (((mstar >> 2) & 63) == t) evt_lds[mstar] = i;

        // ---- cum += row_i; evicted column -> sentinel ----
        int ec = mstar - (t << 2);   // matches (j<<8)|c for the owned column
#pragma unroll
        for (int j = 0; j < 8; ++j) {
            floatx4 nv = cum[j] + rr[j];
#pragma unroll
            for (int c = 0; c < 4; ++c)
                nv[c] = (ec == ((j << 8) | c)) ? -1e30f : nv[c];
            cum[j] = nv;
        }
    }
    // ---- dump evt LDS -> global (single wave, lgkm ordering suffices) ----
#pragma unroll
    for (int j = 0; j < 8; ++j)
        *(int4*)&evt[b * M_ + j * 256 + t * 4] =
            *(const int4*)&evt_lds[j * 256 + t * 4];
}

// ------------------------------------------------------ flash attention
__global__ __launch_bounds__(256) void flash_kernel(
    const u16* __restrict__ Qb, const u16* __restrict__ Kb,
    const u16* __restrict__ Vb, const int* __restrict__ evt,
    u16* __restrict__ Ob)
{
    int bh = blockIdx.y;
    int b = bh >> 4, h = bh & 15;
    int q0 = blockIdx.x * 64;
    int tid = threadIdx.x, lane = tid & 63, w = tid >> 6;
    int quad = lane >> 4, l16 = lane & 15;
    const u16* Qh = Qb + (size_t)bh * N_ * DH_;
    const u16* Kh = Kb + (size_t)bh * N_ * DH_;
    const u16* Vh = Vb + (size_t)bh * N_ * DH_;
    __shared__ __align__(16) u16 sK[64 * 64];
    __shared__ __align__(16) u16 sV[64 * 64];     // transposed [dh][key]
    __shared__ __align__(16) u16 sP[4][16 * 64];  // wave-private P
    __shared__ int sevt[64];

    short8 aq0 = *(const short8*)&Qh[(size_t)(q0 + w * 16 + l16) * 64 + quad * 8];
    short8 aq1 = *(const short8*)&Qh[(size_t)(q0 + w * 16 + l16) * 64 + quad * 8 + 32];

    floatx4 zero = {0.f, 0.f, 0.f, 0.f};
    floatx4 accO[4];
#pragma unroll
    for (int d = 0; d < 4; ++d) accO[d] = zero;
    float m_i[4] = {-1e30f, -1e30f, -1e30f, -1e30f};
    float l_i[4] = {0.f, 0.f, 0.f, 0.f};

    int ktiles = blockIdx.x + 1;
    for (int kt = 0; kt < ktiles; ++kt) {
        int k0 = kt * 64;
#pragma unroll
        for (int it = 0; it < 2; ++it) {
            int e = (tid + it * 256) * 8;
            int r = e >> 6, c = e & 63;
            *(uint4*)&sK[e] = *(const uint4*)&Kh[(size_t)(k0 + r) * 64 + c];
            uint4 vv = *(const uint4*)&Vh[(size_t)(k0 + r) * 64 + c];
            sV[(c + 0) * 64 + r] = (u16)(vv.x & 0xFFFF);
            sV[(c + 1) * 64 + r] = (u16)(vv.x >> 16);
            sV[(c + 2) * 64 + r] = (u16)(vv.y & 0xFFFF);
            sV[(c + 3) * 64 + r] = (u16)(vv.y >> 16);
            sV[(c + 4) * 64 + r] = (u16)(vv.z & 0xFFFF);
            sV[(c + 5) * 64 + r] = (u16)(vv.z >> 16);
            sV[(c + 6) * 64 + r] = (u16)(vv.w & 0xFFFF);
            sV[(c + 7) * 64 + r] = (u16)(vv.w >> 16);
        }
        if (tid < 64) sevt[tid] = evt[b * M_ + k0 + tid];
        __syncthreads();

        floatx4 lg[4];
        int nbase = q0 + w * 16 + quad * 4;
#pragma unroll
        for (int s = 0; s < 4; ++s) {
            floatx4 sc = zero;
            short8 bk0 = *(const short8*)&sK[(s * 16 + l16) * 64 + quad * 8];
            short8 bk1 = *(const short8*)&sK[(s * 16 + l16) * 64 + quad * 8 + 32];
            sc = __builtin_amdgcn_mfma_f32_16x16x32_bf16(aq0, bk0, sc, 0, 0, 0);
            sc = __builtin_amdgcn_mfma_f32_16x16x32_bf16(aq1, bk1, sc, 0, 0, 0);
            int m = k0 + s * 16 + l16;
            int ev = sevt[s * 16 + l16];
#pragma unroll
            for (int r = 0; r < 4; ++r) {
                int n = nbase + r;
                bool keep = (m <= n) && (n < ev);
                lg[s][r] = keep ? sc[r] * 0.125f : -1e30f;
            }
        }
        float mnew[4], scale[4], rs[4];
#pragma unroll
        for (int r = 0; r < 4; ++r) {
            float mx = fmaxf(fmaxf(lg[0][r], lg[1][r]), fmaxf(lg[2][r], lg[3][r]));
#pragma unroll
            for (int d = 1; d < 16; d <<= 1) mx = fmaxf(mx, __shfl_xor(mx, d));
            mnew[r] = fmaxf(m_i[r], mx);
            scale[r] = __expf(m_i[r] - mnew[r]);
            m_i[r] = mnew[r];
            rs[r] = 0.f;
        }
#pragma unroll
        for (int s = 0; s < 4; ++s)
#pragma unroll
            for (int r = 0; r < 4; ++r) {
                float p = __expf(lg[s][r] - mnew[r]);
                rs[r] += p;
                sP[w][(quad * 4 + r) * 64 + s * 16 + l16] = f2b(p);
            }
#pragma unroll
        for (int r = 0; r < 4; ++r) {
            float t_ = rs[r];
#pragma unroll
            for (int d = 1; d < 16; d <<= 1) t_ += __shfl_xor(t_, d);
            l_i[r] = l_i[r] * scale[r] + t_;
        }
#pragma unroll
        for (int dd = 0; dd < 4; ++dd) {
            accO[dd][0] *= scale[0]; accO[dd][1] *= scale[1];
            accO[dd][2] *= scale[2]; accO[dd][3] *= scale[3];
        }
        short8 ap0 = *(const short8*)&sP[w][l16 * 64 + quad * 8];
        short8 ap1 = *(const short8*)&sP[w][l16 * 64 + quad * 8 + 32];
#pragma unroll
        for (int dd = 0; dd < 4; ++dd) {
            short8 bv0 = *(const short8*)&sV[(dd * 16 + l16) * 64 + quad * 8];
            short8 bv1 = *(const short8*)&sV[(dd * 16 + l16) * 64 + quad * 8 + 32];
            accO[dd] = __builtin_amdgcn_mfma_f32_16x16x32_bf16(ap0, bv0, accO[dd], 0, 0, 0);
            accO[dd] = __builtin_amdgcn_mfma_f32_16x16x32_bf16(ap1, bv1, accO[dd], 0, 0, 0);
        }
        __syncthreads();
    }
#pragma unroll
    for (int dd = 0; dd < 4; ++dd)
#pragma unroll
        for (int r = 0; r < 4; ++r) {
            int n = q0 + w * 16 + quad * 4 + r;
            int col = h * 64 + dd * 16 + l16;
            Ob[((size_t)b * N_ + n) * D_ + col] = f2b(accO[dd][r] / l_i[r]);
        }
}

// ---------------------------------------------------------------- launch
extern "C" void kernel_launch(void* const* d_in, const int* in_sizes, int n_in,
                              void* d_out, int out_size, void* d_ws, size_t ws_size,
                              hipStream_t stream)
{
    (void)in_sizes; (void)n_in; (void)out_size; (void)ws_size;
    const float* X  = (const float*)d_in[0];
    const float* Wq = (const float*)d_in[1];
    const float* Wk = (const float*)d_in[2];
    const float* Wv = (const float*)d_in[3];
    const float* Wo = (const float*)d_in[4];
    const float* gq = (const float*)d_in[5];
    const float* bq = (const float*)d_in[6];
    const float* gk = (const float*)d_in[7];
    const float* bk = (const float*)d_in[8];

    char* p = (char*)d_ws;
    const size_t SZ_XH = (size_t)ROWS_ * D_ * 2;
    const size_t SZ_W  = (size_t)D_ * D_ * 2;
    const size_t SZ_Y  = (size_t)ROWS_ * D_ * 4;
    const size_t SZ_PK = (size_t)ROWS_ * D_ * 2;
    const size_t SZ_H0 = (size_t)ROWS_ * 64 * 4;

    size_t o = 0;
    u16* Xhi = (u16*)(p + o); o += SZ_XH;
    u16* Xlo = (u16*)(p + o); o += SZ_XH;
    u16* Wqh = (u16*)(p + o); o += SZ_W;
    u16* Wql = (u16*)(p + o); o += SZ_W;
    u16* Wkh = (u16*)(p + o); o += SZ_W;
    u16* Wkl = (u16*)(p + o); o += SZ_W;
    u16* Wvh = (u16*)(p + o); o += SZ_W;
    u16* Woh = (u16*)(p + o); o += SZ_W;
    float* Yq = (float*)(p + o); size_t oYq = o; o += SZ_Y;
    float* Yk = (float*)(p + o); o += SZ_Y;
    float* Yv = (float*)(p + o); o += SZ_Y;
    u16* Qb = (u16*)(p + o); o += SZ_PK;
    u16* Kb = (u16*)(p + o); o += SZ_PK;
    u16* Vb = (u16*)(p + o); o += SZ_PK;
    float* q0s = (float*)(p + o); o += SZ_H0;
    float* k0s = (float*)(p + o); o += SZ_H0;
    float* Pp  = (float*)(p + o); o += (size_t)B_ * 8 * M_ * 4;
    int* evt   = (int*)(p + o);  o += (size_t)B_ * M_ * 4;
    float* S = (float*)(p + oYq);   // overlay over Yq+Yk (dead after LN)
    u16* Ob  = Xhi;                 // overlay over Xhi (dead after X-GEMMs)

    cast_x_kernel<<<ROWS_ * D_ / (256 * 4), 256, 0, stream>>>(X, Xhi, Xlo);
    dim3 wgrid(32, 32), wblk(32, 32);
    cast_w_kernel<<<wgrid, wblk, 0, stream>>>(Wq, Wqh, Wql, 1);
    cast_w_kernel<<<wgrid, wblk, 0, stream>>>(Wk, Wkh, Wkl, 1);
    cast_w_kernel<<<wgrid, wblk, 0, stream>>>(Wv, Wvh, nullptr, 0);
    cast_w_kernel<<<wgrid, wblk, 0, stream>>>(Wo, Woh, nullptr, 0);

    dim3 ggrid(D_ / 128, ROWS_ / 128);
    gemm_kernel<<<ggrid, 256, 0, stream>>>(Xhi, Xlo, Wqh, Wql, 1, Yq);
    gemm_kernel<<<ggrid, 256, 0, stream>>>(Xhi, Xlo, Wkh, Wkl, 1, Yk);
    gemm_kernel<<<ggrid, 256, 0, stream>>>(Xhi, nullptr, Wvh, nullptr, 0, Yv);

    lnpack_kernel<<<ROWS_, 256, 0, stream>>>(Yq, gq, bq, Qb, q0s, 1);
    lnpack_kernel<<<ROWS_, 256, 0, stream>>>(Yk, gk, bk, Kb, k0s, 1);
    lnpack_kernel<<<ROWS_, 256, 0, stream>>>(Yv, nullptr, nullptr, Vb, nullptr, 0);

    s_kernel<<<dim3(M_ / 16, N_ / 16, B_), dim3(16, 16), 0, stream>>>(q0s, k0s, S);
    p_kernel<<<dim3(M_ / 256, 8, B_), 256, 0, stream>>>(S, Pp);
    evict_kernel<<<B_, 64, 0, stream>>>(S, Pp, evt);

    flash_kernel<<<dim3(N_ / 64, B_ * H_), 256, 0, stream>>>(Qb, Kb, Vb, evt, Ob);
    gemm_kernel<<<ggrid, 256, 0, stream>>>(Ob, nullptr, Woh, nullptr, 0, (float*)d_out);
}

// Round 6
// 1520.758 us; speedup vs baseline: 1.6171x; 1.0126x over previous
//
// MultiheadSelectiveAttentionWithTokenPruning — MI355X round 5
//
// Round-5 change (evict only): get LDS out of the row-streaming path.
// Round 4's ds_reads of global_load_lds-filled LDS made the compiler
// insert its own conservative s_waitcnt vmcnt(0) before the reads —
// draining the JUST-ISSUED prefetch and exposing ~900 cyc of HBM latency
// every iteration (~2250 cyc/iter, VALU only ~240 of it). Now rows are
// double-buffered in REGISTERS via plain global_load_dwordx4 (precise
// per-load vmcnt tracking: the wait covers row i issued 2 steps earlier,
// never the fresh prefetch). argmax runs before the consume for extra
// slack. First-max index scan: per-quad select + min-tree (latency ~30
// cyc vs 128 serial). evt in LDS (write-only in loop), dumped at end.
//
// Pipeline:
//  1  cast_x      : X fp32 -> Xhi/Xlo bf16 (split for bf16x3 GEMM)
//  2  cast_w x4   : W fp32 -> W^T bf16 (hi[+lo for Wq/Wk])
//  3  gemm split  : Yq = X@Wq  (hi*hi + hi*lo + lo*hi)  ~fp32 accuracy
//  4  gemm split  : Yk = X@Wk
//  5  gemm        : Yv = X@Wv  (plain bf16)
//  6-8 lnpack     : LN + pack to (B,H,N,Dh) bf16, head-0 fp32 copies
//  9  s_kernel    : S[b,n,m] = relu(q0.k0/8), causal/diag/col0-zeroed
// 10  p_kernel    : column partial sums of S rows 0..1023
// 11  evict       : 1024 sequential argmax evictions (single wave/batch)
// 12  flash       : all 16 heads, online softmax, mask = causal && n<evt[m]
// 13  gemm        : out = Ob @ Wo -> d_out fp32

#include <hip/hip_runtime.h>

#define B_    2
#define N_    2048
#define D_    1024
#define H_    16
#define DH_   64
#define M_    2048
#define ROWS_ 4096
#define BUD_  1024

typedef unsigned short u16;
typedef unsigned int   u32;
typedef unsigned long long u64;
typedef __attribute__((ext_vector_type(8))) short short8;
typedef __attribute__((ext_vector_type(4))) float floatx4;

__device__ __forceinline__ u16 f2b(float f) {
    u32 u = __float_as_uint(f);
    return (u16)((u + 0x7FFFu + ((u >> 16) & 1u)) >> 16);   // RNE
}
__device__ __forceinline__ float b2f(u16 h) {
    return __uint_as_float(((u32)h) << 16);
}

// ---------------------------------------------------------------- cast X
__global__ __launch_bounds__(256) void cast_x_kernel(
    const float* __restrict__ X, u16* __restrict__ Xhi, u16* __restrict__ Xlo)
{
    int idx = (blockIdx.x * 256 + threadIdx.x) * 4;
    float4 v = *(const float4*)&X[idx];
    u16 h0 = f2b(v.x), h1 = f2b(v.y), h2 = f2b(v.z), h3 = f2b(v.w);
    ushort4 hv; hv.x = h0; hv.y = h1; hv.z = h2; hv.w = h3;
    *(ushort4*)&Xhi[idx] = hv;
    ushort4 lv;
    lv.x = f2b(v.x - b2f(h0)); lv.y = f2b(v.y - b2f(h1));
    lv.z = f2b(v.z - b2f(h2)); lv.w = f2b(v.w - b2f(h3));
    *(ushort4*)&Xlo[idx] = lv;
}

// ------------------------------------------------- cast + transpose W
__global__ __launch_bounds__(1024) void cast_w_kernel(
    const float* __restrict__ W, u16* __restrict__ Whi, u16* __restrict__ Wlo,
    int do_lo)
{
    __shared__ float tile[32][33];
    int tx = threadIdx.x, ty = threadIdx.y;
    int x = blockIdx.x * 32 + tx, y = blockIdx.y * 32 + ty;
    tile[ty][tx] = W[(size_t)y * D_ + x];
    __syncthreads();
    float v = tile[tx][ty];
    int n = blockIdx.x * 32 + ty, k = blockIdx.y * 32 + tx;
    u16 h = f2b(v);
    Whi[(size_t)n * D_ + k] = h;
    if (do_lo) Wlo[(size_t)n * D_ + k] = f2b(v - b2f(h));
}

// ------------------------------------------------------------- GEMM
// C[4096][1024] = A[4096][1024] @ Bt^T   (Bt stored [n][k])
// mode 1: C = Ah*Bh + Ah*Bl + Al*Bh  (bf16x3 split, ~fp32 precision)
__global__ __launch_bounds__(256) void gemm_kernel(
    const u16* __restrict__ Ah, const u16* __restrict__ Al,
    const u16* __restrict__ Bh, const u16* __restrict__ Bl,
    int mode, float* __restrict__ C)
{
    __shared__ __align__(16) u16 sAh[128 * 32];
    __shared__ __align__(16) u16 sBh[128 * 32];
    __shared__ __align__(16) u16 sAl[128 * 32];
    __shared__ __align__(16) u16 sBl[128 * 32];
    int tid = threadIdx.x;
    int lane = tid & 63, wv = tid >> 6;
    int wr = wv >> 1, wc = wv & 1;
    int quad = lane >> 4, l16 = lane & 15;
    int m0 = blockIdx.y * 128, n0 = blockIdx.x * 128;

    floatx4 acc[4][4];
    floatx4 zero = {0.f, 0.f, 0.f, 0.f};
#pragma unroll
    for (int i = 0; i < 4; ++i)
#pragma unroll
        for (int j = 0; j < 4; ++j) acc[i][j] = zero;

    for (int k0 = 0; k0 < 1024; k0 += 32) {
#pragma unroll
        for (int it = 0; it < 2; ++it) {
            int e = (tid + it * 256) * 8;
            int r = e >> 5, c = e & 31;
            *(uint4*)&sAh[e] = *(const uint4*)&Ah[(size_t)(m0 + r) * 1024 + k0 + c];
            *(uint4*)&sBh[e] = *(const uint4*)&Bh[(size_t)(n0 + r) * 1024 + k0 + c];
            if (mode) {
                *(uint4*)&sAl[e] = *(const uint4*)&Al[(size_t)(m0 + r) * 1024 + k0 + c];
                *(uint4*)&sBl[e] = *(const uint4*)&Bl[(size_t)(n0 + r) * 1024 + k0 + c];
            }
        }
        __syncthreads();
        short8 ah[4], al[4], bh[4], bl[4];
#pragma unroll
        for (int x = 0; x < 4; ++x) {
            int ra = (wr * 64 + x * 16 + l16) * 32 + quad * 8;
            int rb = (wc * 64 + x * 16 + l16) * 32 + quad * 8;
            ah[x] = *(const short8*)&sAh[ra];
            bh[x] = *(const short8*)&sBh[rb];
            if (mode) {
                al[x] = *(const short8*)&sAl[ra];
                bl[x] = *(const short8*)&sBl[rb];
            }
        }
#pragma unroll
        for (int mi = 0; mi < 4; ++mi)
#pragma unroll
            for (int ni = 0; ni < 4; ++ni) {
                acc[mi][ni] = __builtin_amdgcn_mfma_f32_16x16x32_bf16(
                    ah[mi], bh[ni], acc[mi][ni], 0, 0, 0);
                if (mode) {
                    acc[mi][ni] = __builtin_amdgcn_mfma_f32_16x16x32_bf16(
                        ah[mi], bl[ni], acc[mi][ni], 0, 0, 0);
                    acc[mi][ni] = __builtin_amdgcn_mfma_f32_16x16x32_bf16(
                        al[mi], bh[ni], acc[mi][ni], 0, 0, 0);
                }
            }
        __syncthreads();
    }
    // C/D layout: col = lane&15, row = (lane>>4)*4 + reg   [verified m89/m91]
#pragma unroll
    for (int mi = 0; mi < 4; ++mi)
#pragma unroll
        for (int ni = 0; ni < 4; ++ni)
#pragma unroll
            for (int r = 0; r < 4; ++r) {
                int row = m0 + wr * 64 + mi * 16 + quad * 4 + r;
                int col = n0 + wc * 64 + ni * 16 + l16;
                C[(size_t)row * 1024 + col] = acc[mi][ni][r];
            }
}

// ----------------------------------------------------- LayerNorm + pack
__global__ __launch_bounds__(256) void lnpack_kernel(
    const float* __restrict__ Y, const float* __restrict__ gamma,
    const float* __restrict__ beta, u16* __restrict__ Pk,
    float* __restrict__ head0, int do_ln)
{
    int r = blockIdx.x;
    int tid = threadIdx.x;
    float4 v = *(const float4*)&Y[(size_t)r * D_ + tid * 4];
    float mu = 0.f, rsig = 1.f;
    __shared__ float sS[4], sQ[4];
    if (do_ln) {
        float s = v.x + v.y + v.z + v.w;
        float q = v.x * v.x + v.y * v.y + v.z * v.z + v.w * v.w;
#pragma unroll
        for (int d = 1; d < 64; d <<= 1) { s += __shfl_xor(s, d); q += __shfl_xor(q, d); }
        if ((tid & 63) == 0) { sS[tid >> 6] = s; sQ[tid >> 6] = q; }
        __syncthreads();
        s = sS[0] + sS[1] + sS[2] + sS[3];
        q = sQ[0] + sQ[1] + sQ[2] + sQ[3];
        mu = s * (1.f / 1024.f);
        float var = q * (1.f / 1024.f) - mu * mu;
        rsig = rsqrtf(var + 1e-5f);
    }
    int b = r >> 11, n = r & 2047;
    float xs[4] = {v.x, v.y, v.z, v.w};
#pragma unroll
    for (int j = 0; j < 4; ++j) {
        int c = tid * 4 + j;
        float val = do_ln ? ((xs[j] - mu) * rsig * gamma[c] + beta[c]) : xs[j];
        int h = c >> 6, dh = c & 63;
        Pk[(((size_t)b * H_ + h) * N_ + n) * DH_ + dh] = f2b(val);
        if (head0 && c < 64) head0[(size_t)r * 64 + c] = val;
    }
}

// -------------------------------------------- head-0 selection scores S
__global__ void s_kernel(const float* __restrict__ q0,
                         const float* __restrict__ k0, float* __restrict__ S)
{
    int b = blockIdx.z;
    int n0 = blockIdx.y * 16, m0 = blockIdx.x * 16;
    int tx = threadIdx.x, ty = threadIdx.y;
    int n = n0 + ty, m = m0 + tx;
    float* out = S + ((size_t)b * N_ + n) * M_ + m;
    if (m0 > n0 + 15) { *out = 0.f; return; }   // fully above diagonal
    __shared__ float sq[16][65], sk[16][65];
    int tid = ty * 16 + tx;
    {
        int rr = tid >> 4, cc = (tid & 15) * 4;
        float4 qa = *(const float4*)&q0[((size_t)b * N_ + n0 + rr) * 64 + cc];
        sq[rr][cc] = qa.x; sq[rr][cc + 1] = qa.y; sq[rr][cc + 2] = qa.z; sq[rr][cc + 3] = qa.w;
        float4 ka = *(const float4*)&k0[((size_t)b * N_ + m0 + rr) * 64 + cc];
        sk[rr][cc] = ka.x; sk[rr][cc + 1] = ka.y; sk[rr][cc + 2] = ka.z; sk[rr][cc + 3] = ka.w;
    }
    __syncthreads();
    float acc = 0.f;
#pragma unroll 8
    for (int d = 0; d < 64; ++d) acc += sq[ty][d] * sk[tx][d];
    float val;
    if (m < n && m != 0) val = fmaxf(acc * 0.125f, 0.f); else val = 0.f;
    *out = val;
}

// -------------------------------- partial column sums of S rows 0..1023
__global__ __launch_bounds__(256) void p_kernel(const float* __restrict__ S,
                                                float* __restrict__ P)
{
    int b = blockIdx.z, c = blockIdx.y;
    int m = blockIdx.x * 256 + threadIdx.x;
    const float* base = S + ((size_t)b * N_ + c * 128) * M_ + m;
    float s = 0.f;
    for (int j = 0; j < 128; ++j) s += base[(size_t)j * M_];
    P[((size_t)b * 8 + c) * M_ + m] = s;
}

// --------------------------------------------- sequential greedy eviction
// Single wave per batch. Lane t owns columns m = j*256 + t*4 + c (j<8,c<4).
// Evicted column -> cum = -1e30 (absorbing: rr>=0 and -1e30+rr rounds back
// to -1e30). Columns m >= i sit at exactly 0 and never win (col 0 is a
// permanent 0-valued candidate with smaller m). Local argmax: fmax tree +
// per-quad first-equal select + min-tree (exact: fmaxf returns an input
// bitwise). Cross-lane: monotone-key u64 (key<<32 | 2048-m) max via DPP
// (row_shr 1/2/4/8 + row_bcast 15/31 -> lane 63) == jnp.argmax tie rules.
// Rows double-buffered in REGISTERS (global_load_dwordx4; compiler emits
// precise vmcnt for the consumed row only). evt in LDS, dumped at end.
#define DPP_MAX64(CTRL)                                                     \
    do {                                                                    \
        u32 lo_ = (u32)pk, hi_ = (u32)(pk >> 32);                           \
        u32 plo_ = (u32)__builtin_amdgcn_update_dpp(                        \
            (int)lo_, (int)lo_, CTRL, 0xf, 0xf, false);                     \
        u32 phi_ = (u32)__builtin_amdgcn_update_dpp(                        \
            (int)hi_, (int)hi_, CTRL, 0xf, 0xf, false);                     \
        u64 ot_ = ((u64)phi_ << 32) | plo_;                                 \
        pk = ot_ > pk ? ot_ : pk;                                           \
    } while (0)

// one eviction step: argmax(cum) -> evt; cum += BUF (sentinel); BUF = row NR
#define EVICT_STEP(BUF, I, NR)                                              \
    do {                                                                    \
        /* local max over 32 owned columns (fmax tree) */                   \
        float g0 = fmaxf(fmaxf(cum[0][0], cum[0][1]), fmaxf(cum[0][2], cum[0][3])); \
        float g1 = fmaxf(fmaxf(cum[1][0], cum[1][1]), fmaxf(cum[1][2], cum[1][3])); \
        float g2 = fmaxf(fmaxf(cum[2][0], cum[2][1]), fmaxf(cum[2][2], cum[2][3])); \
        float g3 = fmaxf(fmaxf(cum[3][0], cum[3][1]), fmaxf(cum[3][2], cum[3][3])); \
        float g4 = fmaxf(fmaxf(cum[4][0], cum[4][1]), fmaxf(cum[4][2], cum[4][3])); \
        float g5 = fmaxf(fmaxf(cum[5][0], cum[5][1]), fmaxf(cum[5][2], cum[5][3])); \
        float g6 = fmaxf(fmaxf(cum[6][0], cum[6][1]), fmaxf(cum[6][2], cum[6][3])); \
        float g7 = fmaxf(fmaxf(cum[7][0], cum[7][1]), fmaxf(cum[7][2], cum[7][3])); \
        float mx = fmaxf(fmaxf(fmaxf(g0, g1), fmaxf(g2, g3)),               \
                         fmaxf(fmaxf(g4, g5), fmaxf(g6, g7)));              \
        /* first (min-e) element equal to mx: per-quad select + min tree */ \
        int q0_, q1_, q2_, q3_, q4_, q5_, q6_, q7_;                         \
        EQ4(q0_, 0) EQ4(q1_, 1) EQ4(q2_, 2) EQ4(q3_, 3)                     \
        EQ4(q4_, 4) EQ4(q5_, 5) EQ4(q6_, 6) EQ4(q7_, 7)                     \
        int be = min(min(min(q0_, q1_), min(q2_, q3_)),                     \
                     min(min(q4_, q5_), min(q6_, q7_)));                    \
        int bestm = ((be >> 2) << 8) | (t << 2) | (be & 3);                 \
        u32 bits = __float_as_uint(mx);                                     \
        u32 key = bits ^ (((u32)((int)bits >> 31)) | 0x80000000u);          \
        u64 pk = ((u64)key << 32) | (u32)(2048 - bestm);                    \
        DPP_MAX64(0x111); DPP_MAX64(0x112); DPP_MAX64(0x114);               \
        DPP_MAX64(0x118); DPP_MAX64(0x142); DPP_MAX64(0x143);               \
        int mlo = __builtin_amdgcn_readlane((int)(u32)(pk & 0xFFFFFFFFu), 63); \
        int mstar = 2048 - mlo;                                             \
        int em = (((mstar >> 2) & 63) == t)                                 \
                     ? (((mstar >> 8) << 2) | (mstar & 3)) : 64;            \
        if (em < 64) evt_lds[mstar] = (I);                                  \
        _Pragma("unroll")                                                   \
        for (int j = 0; j < 8; ++j) {                                       \
            floatx4 nv = cum[j] + BUF[j];                                   \
            _Pragma("unroll")                                               \
            for (int c = 0; c < 4; ++c)                                     \
                nv[c] = (em == j * 4 + c) ? -1e30f : nv[c];                 \
            cum[j] = nv;                                                    \
        }                                                                   \
        size_t ro_ = (size_t)((NR) < 2048 ? (NR) : 2047) * M_;              \
        _Pragma("unroll")                                                   \
        for (int j = 0; j < 8; ++j)                                         \
            BUF[j] = *(const floatx4*)&SbT[ro_ + j * 256];                  \
    } while (0)

#define EQ4(DST, J)                                                         \
    DST = (cum[J][0] == mx) ? (J * 4 + 0)                                   \
        : ((cum[J][1] == mx) ? (J * 4 + 1)                                  \
        : ((cum[J][2] == mx) ? (J * 4 + 2)                                  \
        : ((cum[J][3] == mx) ? (J * 4 + 3) : 63)));

__global__ __launch_bounds__(64) void evict_kernel(
    const float* __restrict__ S, const float* __restrict__ P,
    int* __restrict__ evt)
{
    __shared__ __align__(16) int evt_lds[2048];     // 8 KiB
    int b = blockIdx.x, t = threadIdx.x;
    const float* SbT = S + (size_t)b * N_ * M_ + t * 4;

    floatx4 cum[8];
#pragma unroll
    for (int j = 0; j < 8; ++j) {
        floatx4 s4 = {0.f, 0.f, 0.f, 0.f};
#pragma unroll
        for (int ch = 0; ch < 8; ++ch)
            s4 = s4 + *(const floatx4*)&P[((size_t)b * 8 + ch) * M_ + j * 256 + t * 4];
        cum[j] = s4;
        int4 init = {0x3FFFFFFF, 0x3FFFFFFF, 0x3FFFFFFF, 0x3FFFFFFF};
        *(int4*)&evt_lds[j * 256 + t * 4] = init;
    }
    floatx4 bufA[8], bufB[8];
#pragma unroll
    for (int j = 0; j < 8; ++j)
        bufA[j] = *(const floatx4*)&SbT[(size_t)1024 * M_ + j * 256];
#pragma unroll
    for (int j = 0; j < 8; ++j)
        bufB[j] = *(const floatx4*)&SbT[(size_t)1025 * M_ + j * 256];

    for (int i = BUD_; i < M_; i += 2) {
        EVICT_STEP(bufA, i,     i + 2);
        EVICT_STEP(bufB, i + 1, i + 3);
    }
    // ---- dump evt LDS -> global (single wave, lgkm ordering suffices) ----
#pragma unroll
    for (int j = 0; j < 8; ++j)
        *(int4*)&evt[b * M_ + j * 256 + t * 4] =
            *(const int4*)&evt_lds[j * 256 + t * 4];
}

// ------------------------------------------------------ flash attention
__global__ __launch_bounds__(256) void flash_kernel(
    const u16* __restrict__ Qb, const u16* __restrict__ Kb,
    const u16* __restrict__ Vb, const int* __restrict__ evt,
    u16* __restrict__ Ob)
{
    int bh = blockIdx.y;
    int b = bh >> 4, h = bh & 15;
    int q0 = blockIdx.x * 64;
    int tid = threadIdx.x, lane = tid & 63, w = tid >> 6;
    int quad = lane >> 4, l16 = lane & 15;
    const u16* Qh = Qb + (size_t)bh * N_ * DH_;
    const u16* Kh = Kb + (size_t)bh * N_ * DH_;
    const u16* Vh = Vb + (size_t)bh * N_ * DH_;
    __shared__ __align__(16) u16 sK[64 * 64];
    __shared__ __align__(16) u16 sV[64 * 64];     // transposed [dh][key]
    __shared__ __align__(16) u16 sP[4][16 * 64];  // wave-private P
    __shared__ int sevt[64];

    short8 aq0 = *(const short8*)&Qh[(size_t)(q0 + w * 16 + l16) * 64 + quad * 8];
    short8 aq1 = *(const short8*)&Qh[(size_t)(q0 + w * 16 + l16) * 64 + quad * 8 + 32];

    floatx4 zero = {0.f, 0.f, 0.f, 0.f};
    floatx4 accO[4];
#pragma unroll
    for (int d = 0; d < 4; ++d) accO[d] = zero;
    float m_i[4] = {-1e30f, -1e30f, -1e30f, -1e30f};
    float l_i[4] = {0.f, 0.f, 0.f, 0.f};

    int ktiles = blockIdx.x + 1;
    for (int kt = 0; kt < ktiles; ++kt) {
        int k0 = kt * 64;
#pragma unroll
        for (int it = 0; it < 2; ++it) {
            int e = (tid + it * 256) * 8;
            int r = e >> 6, c = e & 63;
            *(uint4*)&sK[e] = *(const uint4*)&Kh[(size_t)(k0 + r) * 64 + c];
            uint4 vv = *(const uint4*)&Vh[(size_t)(k0 + r) * 64 + c];
            sV[(c + 0) * 64 + r] = (u16)(vv.x & 0xFFFF);
            sV[(c + 1) * 64 + r] = (u16)(vv.x >> 16);
            sV[(c + 2) * 64 + r] = (u16)(vv.y & 0xFFFF);
            sV[(c + 3) * 64 + r] = (u16)(vv.y >> 16);
            sV[(c + 4) * 64 + r] = (u16)(vv.z & 0xFFFF);
            sV[(c + 5) * 64 + r] = (u16)(vv.z >> 16);
            sV[(c + 6) * 64 + r] = (u16)(vv.w & 0xFFFF);
            sV[(c + 7) * 64 + r] = (u16)(vv.w >> 16);
        }
        if (tid < 64) sevt[tid] = evt[b * M_ + k0 + tid];
        __syncthreads();

        floatx4 lg[4];
        int nbase = q0 + w * 16 + quad * 4;
#pragma unroll
        for (int s = 0; s < 4; ++s) {
            floatx4 sc = zero;
            short8 bk0 = *(const short8*)&sK[(s * 16 + l16) * 64 + quad * 8];
            short8 bk1 = *(const short8*)&sK[(s * 16 + l16) * 64 + quad * 8 + 32];
            sc = __builtin_amdgcn_mfma_f32_16x16x32_bf16(aq0, bk0, sc, 0, 0, 0);
            sc = __builtin_amdgcn_mfma_f32_16x16x32_bf16(aq1, bk1, sc, 0, 0, 0);
            int m = k0 + s * 16 + l16;
            int ev = sevt[s * 16 + l16];
#pragma unroll
            for (int r = 0; r < 4; ++r) {
                int n = nbase + r;
                bool keep = (m <= n) && (n < ev);
                lg[s][r] = keep ? sc[r] * 0.125f : -1e30f;
            }
        }
        float mnew[4], scale[4], rs[4];
#pragma unroll
        for (int r = 0; r < 4; ++r) {
            float mx = fmaxf(fmaxf(lg[0][r], lg[1][r]), fmaxf(lg[2][r], lg[3][r]));
#pragma unroll
            for (int d = 1; d < 16; d <<= 1) mx = fmaxf(mx, __shfl_xor(mx, d));
            mnew[r] = fmaxf(m_i[r], mx);
            scale[r] = __expf(m_i[r] - mnew[r]);
            m_i[r] = mnew[r];
            rs[r] = 0.f;
        }
#pragma unroll
        for (int s = 0; s < 4; ++s)
#pragma unroll
            for (int r = 0; r < 4; ++r) {
                float p = __expf(lg[s][r] - mnew[r]);
                rs[r] += p;
                sP[w][(quad * 4 + r) * 64 + s * 16 + l16] = f2b(p);
            }
#pragma unroll
        for (int r = 0; r < 4; ++r) {
            float t_ = rs[r];
#pragma unroll
            for (int d = 1; d < 16; d <<= 1) t_ += __shfl_xor(t_, d);
            l_i[r] = l_i[r] * scale[r] + t_;
        }
#pragma unroll
        for (int dd = 0; dd < 4; ++dd) {
            accO[dd][0] *= scale[0]; accO[dd][1] *= scale[1];
            accO[dd][2] *= scale[2]; accO[dd][3] *= scale[3];
        }
        short8 ap0 = *(const short8*)&sP[w][l16 * 64 + quad * 8];
        short8 ap1 = *(const short8*)&sP[w][l16 * 64 + quad * 8 + 32];
#pragma unroll
        for (int dd = 0; dd < 4; ++dd) {
            short8 bv0 = *(const short8*)&sV[(dd * 16 + l16) * 64 + quad * 8];
            short8 bv1 = *(const short8*)&sV[(dd * 16 + l16) * 64 + quad * 8 + 32];
            accO[dd] = __builtin_amdgcn_mfma_f32_16x16x32_bf16(ap0, bv0, accO[dd], 0, 0, 0);
            accO[dd] = __builtin_amdgcn_mfma_f32_16x16x32_bf16(ap1, bv1, accO[dd], 0, 0, 0);
        }
        __syncthreads();
    }
#pragma unroll
    for (int dd = 0; dd < 4; ++dd)
#pragma unroll
        for (int r = 0; r < 4; ++r) {
            int n = q0 + w * 16 + quad * 4 + r;
            int col = h * 64 + dd * 16 + l16;
            Ob[((size_t)b * N_ + n) * D_ + col] = f2b(accO[dd][r] / l_i[r]);
        }
}

// ---------------------------------------------------------------- launch
extern "C" void kernel_launch(void* const* d_in, const int* in_sizes, int n_in,
                              void* d_out, int out_size, void* d_ws, size_t ws_size,
                              hipStream_t stream)
{
    (void)in_sizes; (void)n_in; (void)out_size; (void)ws_size;
    const float* X  = (const float*)d_in[0];
    const float* Wq = (const float*)d_in[1];
    const float* Wk = (const float*)d_in[2];
    const float* Wv = (const float*)d_in[3];
    const float* Wo = (const float*)d_in[4];
    const float* gq = (const float*)d_in[5];
    const float* bq = (const float*)d_in[6];
    const float* gk = (const float*)d_in[7];
    const float* bk = (const float*)d_in[8];

    char* p = (char*)d_ws;
    const size_t SZ_XH = (size_t)ROWS_ * D_ * 2;
    const size_t SZ_W  = (size_t)D_ * D_ * 2;
    const size_t SZ_Y  = (size_t)ROWS_ * D_ * 4;
    const size_t SZ_PK = (size_t)ROWS_ * D_ * 2;
    const size_t SZ_H0 = (size_t)ROWS_ * 64 * 4;

    size_t o = 0;
    u16* Xhi = (u16*)(p + o); o += SZ_XH;
    u16* Xlo = (u16*)(p + o); o += SZ_XH;
    u16* Wqh = (u16*)(p + o); o += SZ_W;
    u16* Wql = (u16*)(p + o); o += SZ_W;
    u16* Wkh = (u16*)(p + o); o += SZ_W;
    u16* Wkl = (u16*)(p + o); o += SZ_W;
    u16* Wvh = (u16*)(p + o); o += SZ_W;
    u16* Woh = (u16*)(p + o); o += SZ_W;
    float* Yq = (float*)(p + o); size_t oYq = o; o += SZ_Y;
    float* Yk = (float*)(p + o); o += SZ_Y;
    float* Yv = (float*)(p + o); o += SZ_Y;
    u16* Qb = (u16*)(p + o); o += SZ_PK;
    u16* Kb = (u16*)(p + o); o += SZ_PK;
    u16* Vb = (u16*)(p + o); o += SZ_PK;
    float* q0s = (float*)(p + o); o += SZ_H0;
    float* k0s = (float*)(p + o); o += SZ_H0;
    float* Pp  = (float*)(p + o); o += (size_t)B_ * 8 * M_ * 4;
    int* evt   = (int*)(p + o);  o += (size_t)B_ * M_ * 4;
    float* S = (float*)(p + oYq);   // overlay over Yq+Yk (dead after LN)
    u16* Ob  = Xhi;                 // overlay over Xhi (dead after X-GEMMs)

    cast_x_kernel<<<ROWS_ * D_ / (256 * 4), 256, 0, stream>>>(X, Xhi, Xlo);
    dim3 wgrid(32, 32), wblk(32, 32);
    cast_w_kernel<<<wgrid, wblk, 0, stream>>>(Wq, Wqh, Wql, 1);
    cast_w_kernel<<<wgrid, wblk, 0, stream>>>(Wk, Wkh, Wkl, 1);
    cast_w_kernel<<<wgrid, wblk, 0, stream>>>(Wv, Wvh, nullptr, 0);
    cast_w_kernel<<<wgrid, wblk, 0, stream>>>(Wo, Woh, nullptr, 0);

    dim3 ggrid(D_ / 128, ROWS_ / 128);
    gemm_kernel<<<ggrid, 256, 0, stream>>>(Xhi, Xlo, Wqh, Wql, 1, Yq);
    gemm_kernel<<<ggrid, 256, 0, stream>>>(Xhi, Xlo, Wkh, Wkl, 1, Yk);
    gemm_kernel<<<ggrid, 256, 0, stream>>>(Xhi, nullptr, Wvh, nullptr, 0, Yv);

    lnpack_kernel<<<ROWS_, 256, 0, stream>>>(Yq, gq, bq, Qb, q0s, 1);
    lnpack_kernel<<<ROWS_, 256, 0, stream>>>(Yk, gk, bk, Kb, k0s, 1);
    lnpack_kernel<<<ROWS_, 256, 0, stream>>>(Yv, nullptr, nullptr, Vb, nullptr, 0);

    s_kernel<<<dim3(M_ / 16, N_ / 16, B_), dim3(16, 16), 0, stream>>>(q0s, k0s, S);
    p_kernel<<<dim3(M_ / 256, 8, B_), 256, 0, stream>>>(S, Pp);
    evict_kernel<<<B_, 64, 0, stream>>>(S, Pp, evt);

    flash_kernel<<<dim3(N_ / 64, B_ * H_), 256, 0, stream>>>(Qb, Kb, Vb, evt, Ob);
    gemm_kernel<<<ggrid, 256, 0, stream>>>(Ob, nullptr, Woh, nullptr, 0, (float*)d_out);
}